// Round 6
// baseline (165.209 us; speedup 1.0000x reference)
//
#include <hip/hip_runtime.h>
#include <hip/hip_bf16.h>
#include <math.h>

// Problem constants (N, C, H, W) = (4, 256, 64, 64), out_C = 256, FS=3, pad=1, stride=1
#define NB     4
#define CIN    256
#define HH     64
#define WW     64
#define OUTC   256
#define K2     9
#define KTOT   2304                // CIN * K2
#define HWSZ   4096                // HH * WW
#define NSTEPS 72                  // KTOT / 32
#define MTOT   16384               // NB * HWSZ

// K ordering everywhere: k' = tap*256 + c (tap-major).

typedef __attribute__((ext_vector_type(4))) float  floatx4;
typedef __attribute__((ext_vector_type(8))) short  short8;
typedef __attribute__((ext_vector_type(4))) short  short4v;
typedef __attribute__((ext_vector_type(4))) int    intx4;

__device__ __forceinline__ unsigned short f2bf(float f) {
  union { float f; unsigned u; } v; v.f = f;
  unsigned r = v.u + 0x7FFF + ((v.u >> 16) & 1);   // round-to-nearest-even
  return (unsigned short)(r >> 16);
}
__device__ __forceinline__ float b2f(unsigned short s) {
  union { unsigned u; float f; } v; v.u = ((unsigned)s) << 16;
  return v.f;
}

__device__ __forceinline__ void load_lds16(const void* g, void* l) {
  __builtin_amdgcn_global_load_lds(
      (const __attribute__((address_space(1))) unsigned int*)g,
      (__attribute__((address_space(3))) unsigned int*)l, 16, 0, 0);
}

// Workspace layout (bytes):
//   Bw  : [256 oc][2304 k'] bf16 = 1,179,648
//   B2w : [32 oc ][2304 k'] bf16 =   147,456
//   om  : [4][27][64][64] fp32   = 1,769,472   (RAW conv out, no bias/sigmoid)
//   xt  : [4][64][64][256] bf16  = 8,388,608   (channel-last transposed x)
#define WS_BW_OFF   0
#define WS_B2W_OFF  (KTOT * OUTC * 2)
#define WS_OM_OFF   (WS_B2W_OFF + KTOT * 32 * 2)
#define WS_XT_OFF   (WS_OM_OFF + NB * 27 * HWSZ * 4)
#define WS_END      (WS_XT_OFF + NB * HWSZ * CIN * 2)

// ---------------------------------------------------------------------------
// Kernel 0: fused weight-prep (blocks 0..255) + x transpose (blocks 256..511).
// ---------------------------------------------------------------------------
__global__ __launch_bounds__(256) void prep_xpose_kernel(
    const float* __restrict__ dcn_w, const float* __restrict__ offw,
    const float* __restrict__ x,
    unsigned short* __restrict__ Bw, unsigned short* __restrict__ B2w,
    unsigned short* __restrict__ xt) {
  int bid = blockIdx.x;
  if (bid < 256) {
    int oc = bid;
    for (int k = threadIdx.x; k < KTOT; k += 256) {
      int t = k >> 8, c = k & 255;
      Bw[oc * KTOT + k] = f2bf(dcn_w[oc * KTOT + c * 9 + t]);
      if (oc < 32)
        B2w[oc * KTOT + k] = (oc < 27) ? f2bf(offw[oc * KTOT + c * 9 + t])
                                       : (unsigned short)0;
    }
  } else {
    __shared__ unsigned short T[64 * 266];   // [w][c], pad 266
    int b2 = bid - 256;
    int img = b2 >> 6, h = b2 & 63;
    const float* xp = x + (size_t)img * CIN * HWSZ + h * 64;
    int tid = threadIdx.x;
    int w = tid & 63, cq = tid >> 6;
    for (int cb = 0; cb < 256; cb += 4) {
      int c = cb + cq;
      T[w * 266 + c] = f2bf(xp[(size_t)c * HWSZ + w]);   // lanes=w: coalesced
    }
    __syncthreads();
    int w2 = tid >> 2, cg = (tid & 3) << 6;
    unsigned short* o = xt + ((size_t)(img * 64 + h) * 64 + w2) * 256 + cg;
#pragma unroll
    for (int i = 0; i < 64; i += 8) {
      short8 v = *(short8*)&T[w2 * 266 + cg + i];
      *(short8*)(o + i) = v;
    }
  }
}

// ---------------------------------------------------------------------------
// Kernel 1: offset conv, streaming register-fragment MFMA (no LDS, no barrier).
// Grid = MTOT/32 = 512 blocks, 256 thr. Writes RAW om.
// ---------------------------------------------------------------------------
__global__ __launch_bounds__(256) void conv_offset_stream(
    const unsigned short* __restrict__ xt, const unsigned short* __restrict__ B2w,
    float* __restrict__ om) {
  int tid = threadIdx.x, lane = tid & 63, q = tid >> 6;
  int qm = q & 1, qn = q >> 1;
  int quad = lane >> 4, l15 = lane & 15;
  int mbase = blockIdx.x * 32 + qm * 16;
  int mrow  = mbase + l15;
  int w = mrow & 63, h = (mrow >> 6) & 63, img = mrow >> 12;
  const unsigned short* xn = xt + (size_t)img * HWSZ * 256;
  int ocr = qn * 16 + l15;
  const unsigned short* bbase = B2w + ocr * KTOT + quad * 8;

  floatx4 acc = {0.f, 0.f, 0.f, 0.f};
  for (int s = 0; s < NSTEPS; ++s) {
    int t  = s >> 3;
    int cb = ((s & 7) << 5) + (quad << 3);
    int dy = t / 3 - 1, dx = t % 3 - 1;
    int y = h + dy, xx = w + dx;
    bool inb = ((unsigned)y < 64u) && ((unsigned)xx < 64u);
    short8 af = {0, 0, 0, 0, 0, 0, 0, 0};
    if (inb) af = *(const short8*)(xn + ((size_t)(y * 64 + xx)) * 256 + cb);
    short8 bf = *(const short8*)(bbase + s * 32);
    acc = __builtin_amdgcn_mfma_f32_16x16x32_bf16(af, bf, acc, 0, 0, 0);
  }
  if (ocr < 27) {
    int m0 = mbase + quad * 4;
    int img2 = m0 >> 12, hw = m0 & 4095;
    float4 vv = make_float4(acc[0], acc[1], acc[2], acc[3]);
    *(float4*)&om[(img2 * 27 + ocr) * HWSZ + hw] = vv;
  }
}

// ---------------------------------------------------------------------------
// Kernel 2: FUSED deformable sampling + main GEMM, v2.
// Block: M=64 (one (img,h) row), N=128 (half the oc), K=2304.
// Grid 512 (2 blocks/CU for inter-block latency overlap), 512 thr (8 waves,
// capped at 4 waves/EU -> VGPR<=128). Wave q: qm=q&3 (16 m), qn=q>>2 (64 oc)
// -> 1m x 4n 16x16 tiles, 8 MFMA/step (2 ks halves).
// Per step each thread samples 1m x 8c (4 coalesced 16B corner loads);
// NEXT step's corner loads are issued before the pre-MFMA barrier so their
// latency rides the same vmcnt drain as the B load_lds16 staging.
// ---------------------------------------------------------------------------
__global__ __launch_bounds__(512, 4) void dcn_fused_kernel(
    const unsigned short* __restrict__ xt, const float* __restrict__ om,
    const float* __restrict__ ob, const unsigned short* __restrict__ Bw,
    float* __restrict__ out) {
  __shared__ unsigned short Ald[64 * 64];     //  8 KB
  __shared__ unsigned short Bld[128 * 64];    // 16 KB
  __shared__ intx4  sOff[576];                //  9 KB  (corner short-offsets)
  __shared__ float4 sWt[576];                 //  9 KB  (mask-premult weights)

  int bid = blockIdx.x;                 // 0..511
  int row = bid >> 1;                   // (img,h)
  int nb  = bid & 1;
  int img = row >> 6, h = row & 63;
  int M0  = row * 64;
  int N0  = nb * 128;
  const unsigned short* xb = xt + (size_t)img * HWSZ * 256;
  const float* omn = om + img * (27 * HWSZ);

  int tid  = threadIdx.x;
  int lane = tid & 63, q = tid >> 6;    // q 0..7
  int qm = q & 3, qn = q >> 2;          // 4 m-tiles x 2 n-groups
  int quad = lane >> 4, l15 = lane & 15;

  // ---- bilinear params: 9 taps x 64 w ----
  for (int v = tid; v < 576; v += 512) {
    int w = v & 63, t = v >> 6;
    int ky = t / 3, kx = t % 3;
    int sp = h * 64 + w;
    float offy = omn[(2 * t) * HWSZ + sp] + ob[2 * t];
    float offx = omn[(2 * t + 1) * HWSZ + sp] + ob[2 * t + 1];
    float mraw = omn[(18 + t) * HWSZ + sp] + ob[18 + t];
    float mv   = 1.0f / (1.0f + __expf(-mraw));
    float him  = (float)(h - 1 + ky) + offy;
    float wim  = (float)(w - 1 + kx) + offx;
    float y0f = floorf(him), x0f = floorf(wim);
    float lh = him - y0f, lw = wim - x0f;
    int y0 = (int)y0f, x0i = (int)x0f;
    bool vy0 = (y0 >= 0) && (y0 < HH);
    bool vy1 = (y0 + 1 >= 0) && (y0 + 1 < HH);
    bool vx0 = (x0i >= 0) && (x0i < WW);
    bool vx1 = (x0i + 1 >= 0) && (x0i + 1 < WW);
    float hh_ = 1.0f - lh, hw_ = 1.0f - lw;
    float4 wt;
    wt.x = (vy0 && vx0) ? hh_ * hw_ * mv : 0.0f;
    wt.y = (vy0 && vx1) ? hh_ * lw  * mv : 0.0f;
    wt.z = (vy1 && vx0) ? lh  * hw_ * mv : 0.0f;
    wt.w = (vy1 && vx1) ? lh  * lw  * mv : 0.0f;
    int y0c = min(max(y0, 0), 63), y1c = min(max(y0 + 1, 0), 63);
    int x0c = min(max(x0i, 0), 63), x1c = min(max(x0i + 1, 0), 63);
    intx4 ii = {(y0c * 64 + x0c) << 8, (y0c * 64 + x1c) << 8,
                (y1c * 64 + x0c) << 8, (y1c * 64 + x1c) << 8};
    sOff[v] = ii;
    sWt[v]  = wt;
  }

  floatx4 acc[4];
#pragma unroll
  for (int nj = 0; nj < 4; ++nj) acc[nj] = (floatx4){0.f, 0.f, 0.f, 0.f};

  int sm = tid >> 3, scg = tid & 7;      // A-sample: m row (0..63), 8-c chunk
  int srow = lane >> 3, schk = lane & 7; // B-stage lane split

  __syncthreads();                       // params ready

  // ---- preload step 0 corner data ----
  float4 cwt = sWt[sm];
  short8 r0, r1, r2, r3;
  {
    intx4 coff = sOff[sm];
    int cbeg = scg << 3;                 // t=0, cc=0
    r0 = *(const short8*)(xb + coff.x + cbeg);
    r1 = *(const short8*)(xb + coff.y + cbeg);
    r2 = *(const short8*)(xb + coff.z + cbeg);
    r3 = *(const short8*)(xb + coff.w + cbeg);
  }

  for (int sidx = 0; sidx < 36; ++sidx) {
    int t = sidx >> 2, cc = sidx & 3;
    int tk = t << 8, c0 = cc << 6;
    __syncthreads();                     // prev MFMA done reading Ald/Bld
    // ---- A: pack current corner regs, swizzled ds_write_b128 ----
    {
      short8 pk;
#pragma unroll
      for (int j = 0; j < 8; ++j) {
        float v = cwt.x * b2f((unsigned short)r0[j]) +
                  cwt.y * b2f((unsigned short)r1[j]) +
                  cwt.z * b2f((unsigned short)r2[j]) +
                  cwt.w * b2f((unsigned short)r3[j]);
        pk[j] = (short)f2bf(v);
      }
      *(short8*)&Ald[sm * 64 + ((scg ^ (sm & 7)) << 3)] = pk;
    }
    // ---- B: 128 rows x 64 c via load_lds16, XOR-chunk swizzle ----
#pragma unroll
    for (int it = 0; it < 2; ++it) {
      int rb = q * 16 + it * 8;
      int r  = rb + srow;
      const unsigned short* g =
          Bw + (size_t)(N0 + r) * KTOT + tk + c0 + ((schk ^ (r & 7)) << 3);
      load_lds16(g, &Bld[rb * 64]);
    }
    // ---- prefetch next step's corner data (rides the barrier drain) ----
    if (sidx < 35) {
      int ns = sidx + 1;
      int nt = ns >> 2, ncc = ns & 3;
      intx4 coff = sOff[nt * 64 + sm];
      cwt = sWt[nt * 64 + sm];
      int cbeg = (ncc << 6) + (scg << 3);
      r0 = *(const short8*)(xb + coff.x + cbeg);
      r1 = *(const short8*)(xb + coff.y + cbeg);
      r2 = *(const short8*)(xb + coff.z + cbeg);
      r3 = *(const short8*)(xb + coff.w + cbeg);
    }
    __syncthreads();                     // stage complete (drains vm+lgkm)
    // ---- 8 MFMA ----
#pragma unroll
    for (int ks = 0; ks < 2; ++ks) {
      int cbase = ks * 4 + quad;
      short8 a;
      {
        int r = qm * 16 + l15;
        a = *(short8*)&Ald[r * 64 + ((cbase ^ (r & 7)) << 3)];
      }
#pragma unroll
      for (int nj = 0; nj < 4; ++nj) {
        int r = qn * 64 + nj * 16 + l15;
        short8 b = *(short8*)&Bld[r * 64 + ((cbase ^ (r & 7)) << 3)];
        acc[nj] = __builtin_amdgcn_mfma_f32_16x16x32_bf16(a, b, acc[nj], 0, 0, 0);
      }
    }
  }

  // ---- epilogue ----
  int m0 = M0 + qm * 16 + quad * 4;
  int img2 = m0 >> 12, hw = m0 & 4095;
#pragma unroll
  for (int nj = 0; nj < 4; ++nj) {
    int oc = N0 + qn * 64 + nj * 16 + l15;
    float4 vv = make_float4(acc[nj][0], acc[nj][1], acc[nj][2], acc[nj][3]);
    *(float4*)&out[((size_t)img2 * OUTC + oc) * HWSZ + hw] = vv;
  }
}

// ===========================================================================
// FALLBACK PATH (round-2 fused kernels) — only if ws is too small.
// ===========================================================================
__global__ __launch_bounds__(256) void conv_offset_kernel(
    const float* __restrict__ x, const unsigned short* __restrict__ B2w,
    const float* __restrict__ ob, float* __restrict__ om) {
  __shared__ unsigned short A_lds[64 * 40];
  __shared__ unsigned short B_lds[32 * 40];
  int bid = blockIdx.x;
  int n = bid >> 6, h = bid & 63;
  int tid = threadIdx.x, lane = tid & 63, q = tid >> 6;
  const float* xn = x + n * (CIN * HWSZ);
  floatx4 acc0 = {0.f, 0.f, 0.f, 0.f}, acc1 = {0.f, 0.f, 0.f, 0.f};
  int w = tid & 63, cg = tid >> 6, ocb = tid >> 3, part = tid & 7;
  for (int s = 0; s < NSTEPS; ++s) {
    int t = s >> 3, c0 = (s & 7) << 5;
    int dy = t / 3 - 1, dx = t % 3 - 1;
    __syncthreads();
    {
      int y = h + dy, xx = w + dx;
      bool inb = ((unsigned)y < 64u) && ((unsigned)xx < 64u);
      const float* xb = xn + (c0 + cg * 8) * HWSZ + y * 64 + xx;
      short8 pk;
#pragma unroll
      for (int j = 0; j < 8; ++j) { float v = inb ? xb[j * HWSZ] : 0.0f; pk[j] = (short)f2bf(v); }
      *(short8*)&A_lds[w * 40 + cg * 8] = pk;
    }
    { const unsigned short* bp = B2w + ocb * KTOT + (t << 8) + c0 + part * 4;
      *(short4v*)&B_lds[ocb * 40 + part * 4] = *(const short4v*)bp; }
    __syncthreads();
    int fr = (lane >> 4) * 8;
    short8 af  = *(short8*)&A_lds[(q * 16 + (lane & 15)) * 40 + fr];
    short8 bf0 = *(short8*)&B_lds[((lane & 15)) * 40 + fr];
    short8 bf1 = *(short8*)&B_lds[(16 + (lane & 15)) * 40 + fr];
    acc0 = __builtin_amdgcn_mfma_f32_16x16x32_bf16(af, bf0, acc0, 0, 0, 0);
    acc1 = __builtin_amdgcn_mfma_f32_16x16x32_bf16(af, bf1, acc1, 0, 0, 0);
  }
  int g = lane >> 4;
#pragma unroll
  for (int nt = 0; nt < 2; ++nt) {
    floatx4 a = nt ? acc1 : acc0;
    int oc = nt * 16 + (lane & 15);
    if (oc < 27) {
      float bias = ob[oc];
#pragma unroll
      for (int r = 0; r < 4; ++r) {
        int wm = q * 16 + g * 4 + r;
        float val = a[r] + bias;
        if (oc >= 18) val = 1.0f / (1.0f + __expf(-val));
        om[((n * 27 + oc) << 12) + h * 64 + wm] = val;
      }
    }
  }
}

__global__ __launch_bounds__(256) void dcn_main_kernel(
    const float* __restrict__ x, const float* __restrict__ om,
    const unsigned short* __restrict__ Bw, float* __restrict__ out) {
  __shared__ unsigned short A_lds[32 * 40];
  __shared__ unsigned short B_lds[256 * 40];
  __shared__ int    sY[288];
  __shared__ int    sX[288];
  __shared__ float4 sW[288];
  int bid = blockIdx.x;
  int n = bid >> 7, rem = bid & 127, h = rem >> 1, w0 = (rem & 1) << 5;
  int tid = threadIdx.x, lane = tid & 63, q = tid >> 6;
  const float* xn  = x + n * (CIN * HWSZ);
  const float* omn = om + n * (27 * HWSZ);
  for (int v = tid; v < 288; v += 256) {
    int m = v & 31, t = v >> 5;
    int ky = t / 3, kx = t % 3;
    int wg = w0 + m, sp = h * 64 + wg;
    float offy = omn[(2 * t) * HWSZ + sp];
    float offx = omn[(2 * t + 1) * HWSZ + sp];
    float mv   = omn[(18 + t) * HWSZ + sp];
    float him = (float)(h - 1 + ky) + offy;
    float wim = (float)(wg - 1 + kx) + offx;
    float y0f = floorf(him), x0f = floorf(wim);
    float lh = him - y0f, lw = wim - x0f;
    int y0 = (int)y0f, x0i = (int)x0f;
    bool vy0 = (y0 >= 0) && (y0 < HH), vy1 = (y0 + 1 >= 0) && (y0 + 1 < HH);
    bool vx0 = (x0i >= 0) && (x0i < WW), vx1 = (x0i + 1 >= 0) && (x0i + 1 < WW);
    float hh_ = 1.0f - lh, hw_ = 1.0f - lw;
    float4 wt;
    wt.x = (vy0 && vx0) ? hh_ * hw_ * mv : 0.0f;
    wt.y = (vy0 && vx1) ? hh_ * lw  * mv : 0.0f;
    wt.z = (vy1 && vx0) ? lh  * hw_ * mv : 0.0f;
    wt.w = (vy1 && vx1) ? lh  * lw  * mv : 0.0f;
    sY[v] = y0; sX[v] = x0i; sW[v] = wt;
  }
  floatx4 acc[2][4];
#pragma unroll
  for (int mi = 0; mi < 2; ++mi)
#pragma unroll
    for (int nj = 0; nj < 4; ++nj) acc[mi][nj] = (floatx4){0.f, 0.f, 0.f, 0.f};
  int m = tid & 31, cg = tid >> 5, n0 = q * 64;
  for (int s = 0; s < NSTEPS; ++s) {
    int t = s >> 3, c0 = (s & 7) << 5;
    __syncthreads();
    {
      int p = t * 32 + m;
      int y0 = sY[p], x0i = sX[p];
      float4 wt = sW[p];
      int y0c = min(max(y0, 0), 63), y1c = min(max(y0 + 1, 0), 63);
      int x0c = min(max(x0i, 0), 63), x1c = min(max(x0i + 1, 0), 63);
      int i00 = y0c * 64 + x0c, i01 = y0c * 64 + x1c;
      int i10 = y1c * 64 + x0c, i11 = y1c * 64 + x1c;
      const float* xb = xn + (c0 + cg * 4) * HWSZ;
      short4v pk;
#pragma unroll
      for (int j = 0; j < 4; ++j) {
        const float* xc = xb + j * HWSZ;
        float v = wt.x * xc[i00] + wt.y * xc[i01] + wt.z * xc[i10] + wt.w * xc[i11];
        pk[j] = (short)f2bf(v);
      }
      *(short4v*)&A_lds[m * 40 + cg * 4] = pk;
    }
    {
      const short8* bp = (const short8*)(Bw + tid * KTOT + (t << 8) + c0);
      short8 b0 = bp[0], b1 = bp[1], b2 = bp[2], b3 = bp[3];
      short8* dst = (short8*)&B_lds[tid * 40];
      dst[0] = b0; dst[1] = b1; dst[2] = b2; dst[3] = b3;
    }
    __syncthreads();
    int fr = (lane >> 4) * 8;
    short8 a0 = *(short8*)&A_lds[((lane & 15)) * 40 + fr];
    short8 a1 = *(short8*)&A_lds[(16 + (lane & 15)) * 40 + fr];
#pragma unroll
    for (int nj = 0; nj < 4; ++nj) {
      short8 bfp = *(short8*)&B_lds[(n0 + nj * 16 + (lane & 15)) * 40 + fr];
      acc[0][nj] = __builtin_amdgcn_mfma_f32_16x16x32_bf16(a0, bfp, acc[0][nj], 0, 0, 0);
      acc[1][nj] = __builtin_amdgcn_mfma_f32_16x16x32_bf16(a1, bfp, acc[1][nj], 0, 0, 0);
    }
  }
  int g = lane >> 4;
#pragma unroll
  for (int mi = 0; mi < 2; ++mi) {
    int wm = w0 + mi * 16 + g * 4;
#pragma unroll
    for (int nj = 0; nj < 4; ++nj) {
      int oc = n0 + nj * 16 + (lane & 15);
      float4 vv = make_float4(acc[mi][nj][0], acc[mi][nj][1],
                              acc[mi][nj][2], acc[mi][nj][3]);
      *(float4*)&out[((n * OUTC + oc) << 12) + h * 64 + wm] = vv;
    }
  }
}

// ---------------------------------------------------------------------------
extern "C" void kernel_launch(void* const* d_in, const int* in_sizes, int n_in,
                              void* d_out, int out_size, void* d_ws, size_t ws_size,
                              hipStream_t stream) {
  const float* x     = (const float*)d_in[0];
  const float* offw  = (const float*)d_in[1];
  const float* ob    = (const float*)d_in[2];
  const float* dcn_w = (const float*)d_in[3];
  float* out = (float*)d_out;

  unsigned short* Bw  = (unsigned short*)((char*)d_ws + WS_BW_OFF);
  unsigned short* B2w = (unsigned short*)((char*)d_ws + WS_B2W_OFF);
  float*          omb = (float*)((char*)d_ws + WS_OM_OFF);
  unsigned short* xtb = (unsigned short*)((char*)d_ws + WS_XT_OFF);

  if (ws_size >= (size_t)WS_END) {
    // main path: 3 launches, no A materialization
    prep_xpose_kernel<<<512, 256, 0, stream>>>(dcn_w, offw, x, Bw, B2w, xtb);
    conv_offset_stream<<<MTOT / 32, 256, 0, stream>>>(xtb, B2w, omb);
    dcn_fused_kernel<<<512, 512, 0, stream>>>(xtb, omb, ob, Bw, out);
  } else {
    // fallback: round-2 fused kernels (needs only ~3.1 MB of ws)
    prep_xpose_kernel<<<256, 256, 0, stream>>>(dcn_w, offw, x, Bw, B2w, xtb);
    conv_offset_kernel<<<NB * HH, 256, 0, stream>>>(x, B2w, ob, omb);
    dcn_main_kernel<<<NB * HH * 2, 256, 0, stream>>>(x, omb, Bw, out);
  }
}

// Round 7
// 159.341 us; speedup vs baseline: 1.0368x; 1.0368x over previous
//
#include <hip/hip_runtime.h>
#include <hip/hip_bf16.h>
#include <math.h>

// Problem constants (N, C, H, W) = (4, 256, 64, 64), out_C = 256, FS=3, pad=1, stride=1
#define NB     4
#define CIN    256
#define HH     64
#define WW     64
#define OUTC   256
#define K2     9
#define KTOT   2304                // CIN * K2
#define HWSZ   4096                // HH * WW
#define NSTEPS 72                  // KTOT / 32
#define MTOT   16384               // NB * HWSZ

// K ordering everywhere: k' = tap*256 + c (tap-major).

typedef __attribute__((ext_vector_type(4))) float  floatx4;
typedef __attribute__((ext_vector_type(8))) short  short8;
typedef __attribute__((ext_vector_type(4))) short  short4v;
typedef __attribute__((ext_vector_type(4))) int    intx4;

__device__ __forceinline__ unsigned short f2bf(float f) {
  union { float f; unsigned u; } v; v.f = f;
  unsigned r = v.u + 0x7FFF + ((v.u >> 16) & 1);   // round-to-nearest-even
  return (unsigned short)(r >> 16);
}
__device__ __forceinline__ float b2f(unsigned short s) {
  union { unsigned u; float f; } v; v.u = ((unsigned)s) << 16;
  return v.f;
}

__device__ __forceinline__ void load_lds16(const void* g, void* l) {
  __builtin_amdgcn_global_load_lds(
      (const __attribute__((address_space(1))) unsigned int*)g,
      (__attribute__((address_space(3))) unsigned int*)l, 16, 0, 0);
}

// Workspace layout (bytes):
//   Bw  : [256 oc][2304 k'] bf16 = 1,179,648
//   B2w : [32 oc ][2304 k'] bf16 =   147,456
//   om  : [4][27][64][64] fp32   = 1,769,472   (RAW conv out, no bias/sigmoid)
//   xt  : [4][64][64][256] bf16  = 8,388,608   (channel-last transposed x)
#define WS_BW_OFF   0
#define WS_B2W_OFF  (KTOT * OUTC * 2)
#define WS_OM_OFF   (WS_B2W_OFF + KTOT * 32 * 2)
#define WS_XT_OFF   (WS_OM_OFF + NB * 27 * HWSZ * 4)
#define WS_END      (WS_XT_OFF + NB * HWSZ * CIN * 2)

// ---------------------------------------------------------------------------
// Kernel 0: fused weight-prep (blocks 0..255) + x transpose (blocks 256..511).
// ---------------------------------------------------------------------------
__global__ __launch_bounds__(256) void prep_xpose_kernel(
    const float* __restrict__ dcn_w, const float* __restrict__ offw,
    const float* __restrict__ x,
    unsigned short* __restrict__ Bw, unsigned short* __restrict__ B2w,
    unsigned short* __restrict__ xt) {
  int bid = blockIdx.x;
  if (bid < 256) {
    int oc = bid;
    for (int k = threadIdx.x; k < KTOT; k += 256) {
      int t = k >> 8, c = k & 255;
      Bw[oc * KTOT + k] = f2bf(dcn_w[oc * KTOT + c * 9 + t]);
      if (oc < 32)
        B2w[oc * KTOT + k] = (oc < 27) ? f2bf(offw[oc * KTOT + c * 9 + t])
                                       : (unsigned short)0;
    }
  } else {
    __shared__ unsigned short T[64 * 266];   // [w][c], pad 266
    int b2 = bid - 256;
    int img = b2 >> 6, h = b2 & 63;
    const float* xp = x + (size_t)img * CIN * HWSZ + h * 64;
    int tid = threadIdx.x;
    int w = tid & 63, cq = tid >> 6;
    for (int cb = 0; cb < 256; cb += 4) {
      int c = cb + cq;
      T[w * 266 + c] = f2bf(xp[(size_t)c * HWSZ + w]);   // lanes=w: coalesced
    }
    __syncthreads();
    int w2 = tid >> 2, cg = (tid & 3) << 6;
    unsigned short* o = xt + ((size_t)(img * 64 + h) * 64 + w2) * 256 + cg;
#pragma unroll
    for (int i = 0; i < 64; i += 8) {
      short8 v = *(short8*)&T[w2 * 266 + cg + i];
      *(short8*)(o + i) = v;
    }
  }
}

// ---------------------------------------------------------------------------
// Kernel 1: offset conv, streaming register-fragment MFMA (no LDS, no barrier).
// Grid = MTOT/32 = 512 blocks, 256 thr. Writes RAW om.
// ---------------------------------------------------------------------------
__global__ __launch_bounds__(256) void conv_offset_stream(
    const unsigned short* __restrict__ xt, const unsigned short* __restrict__ B2w,
    float* __restrict__ om) {
  int tid = threadIdx.x, lane = tid & 63, q = tid >> 6;
  int qm = q & 1, qn = q >> 1;
  int quad = lane >> 4, l15 = lane & 15;
  int mbase = blockIdx.x * 32 + qm * 16;
  int mrow  = mbase + l15;
  int w = mrow & 63, h = (mrow >> 6) & 63, img = mrow >> 12;
  const unsigned short* xn = xt + (size_t)img * HWSZ * 256;
  int ocr = qn * 16 + l15;
  const unsigned short* bbase = B2w + ocr * KTOT + quad * 8;

  floatx4 acc = {0.f, 0.f, 0.f, 0.f};
  for (int s = 0; s < NSTEPS; ++s) {
    int t  = s >> 3;
    int cb = ((s & 7) << 5) + (quad << 3);
    int dy = t / 3 - 1, dx = t % 3 - 1;
    int y = h + dy, xx = w + dx;
    bool inb = ((unsigned)y < 64u) && ((unsigned)xx < 64u);
    short8 af = {0, 0, 0, 0, 0, 0, 0, 0};
    if (inb) af = *(const short8*)(xn + ((size_t)(y * 64 + xx)) * 256 + cb);
    short8 bf = *(const short8*)(bbase + s * 32);
    acc = __builtin_amdgcn_mfma_f32_16x16x32_bf16(af, bf, acc, 0, 0, 0);
  }
  if (ocr < 27) {
    int m0 = mbase + quad * 4;
    int img2 = m0 >> 12, hw = m0 & 4095;
    float4 vv = make_float4(acc[0], acc[1], acc[2], acc[3]);
    *(float4*)&om[(img2 * 27 + ocr) * HWSZ + hw] = vv;
  }
}

// ---------------------------------------------------------------------------
// Kernel 2: FUSED deformable sampling + main GEMM, v3.
// Block: M=64 (one (img,h) row), N=256 (ALL oc -> sample-once), K=2304.
// Grid 256, 1024 thr (16 waves, 4/SIMD). Double-buffered Ald/Bld, ONE barrier
// per K-step: waves 0-7 sample A (corner regs ping-pong, loads for step s+2
// issued at step s), waves 8-15 DMA B for step s+1, all 16 waves MFMA step s.
// The barrier's vmcnt drain waits on work that had the whole MFMA phase to
// complete -> the m97-style stall is structurally hidden.
// Wave q: qm=q&3 (16 m), qn=q>>2 (64 oc) -> 1m x 4n tiles, 8 MFMA/step.
// ---------------------------------------------------------------------------
__global__ __launch_bounds__(1024, 4) void dcn_fused_kernel(
    const unsigned short* __restrict__ xt, const float* __restrict__ om,
    const float* __restrict__ ob, const unsigned short* __restrict__ Bw,
    float* __restrict__ out) {
  __shared__ unsigned short Ald[2][64 * 64];     // 16 KB
  __shared__ unsigned short Bld[2][256 * 64];    // 64 KB
  __shared__ intx4  sOff[576];                   //  9 KB
  __shared__ float4 sWt[576];                    //  9 KB

  int bid = blockIdx.x;                 // 0..255 = (img,h)
  int img = bid >> 6, h = bid & 63;
  int M0  = bid * 64;
  const unsigned short* xb = xt + (size_t)img * HWSZ * 256;
  const float* omn = om + img * (27 * HWSZ);

  int tid  = threadIdx.x;
  int lane = tid & 63, q = tid >> 6;    // q 0..15
  int qm = q & 3, qn = q >> 2;          // 4 m-tiles x 4 n-groups
  int quad = lane >> 4, l15 = lane & 15;
  bool samp = (q < 8);
  int wsid = q - 8;                     // stager wave id 0..7

  // ---- bilinear params: 9 taps x 64 w ----
  if (tid < 576) {
    int v = tid;
    int w = v & 63, t = v >> 6;
    int ky = t / 3, kx = t % 3;
    int sp = h * 64 + w;
    float offy = omn[(2 * t) * HWSZ + sp] + ob[2 * t];
    float offx = omn[(2 * t + 1) * HWSZ + sp] + ob[2 * t + 1];
    float mraw = omn[(18 + t) * HWSZ + sp] + ob[18 + t];
    float mv   = 1.0f / (1.0f + __expf(-mraw));
    float him  = (float)(h - 1 + ky) + offy;
    float wim  = (float)(w - 1 + kx) + offx;
    float y0f = floorf(him), x0f = floorf(wim);
    float lh = him - y0f, lw = wim - x0f;
    int y0 = (int)y0f, x0i = (int)x0f;
    bool vy0 = (y0 >= 0) && (y0 < HH);
    bool vy1 = (y0 + 1 >= 0) && (y0 + 1 < HH);
    bool vx0 = (x0i >= 0) && (x0i < WW);
    bool vx1 = (x0i + 1 >= 0) && (x0i + 1 < WW);
    float hh_ = 1.0f - lh, hw_ = 1.0f - lw;
    float4 wt;
    wt.x = (vy0 && vx0) ? hh_ * hw_ * mv : 0.0f;
    wt.y = (vy0 && vx1) ? hh_ * lw  * mv : 0.0f;
    wt.z = (vy1 && vx0) ? lh  * hw_ * mv : 0.0f;
    wt.w = (vy1 && vx1) ? lh  * lw  * mv : 0.0f;
    int y0c = min(max(y0, 0), 63), y1c = min(max(y0 + 1, 0), 63);
    int x0c = min(max(x0i, 0), 63), x1c = min(max(x0i + 1, 0), 63);
    intx4 ii = {(y0c * 64 + x0c) << 8, (y0c * 64 + x1c) << 8,
                (y1c * 64 + x0c) << 8, (y1c * 64 + x1c) << 8};
    sOff[v] = ii;
    sWt[v]  = wt;
  }

  floatx4 acc[4];
#pragma unroll
  for (int nj = 0; nj < 4; ++nj) acc[nj] = (floatx4){0.f, 0.f, 0.f, 0.f};

  int sm = tid >> 3, scg = tid & 7;      // sampler: m row (0..63), 8-c chunk
  int srow = lane >> 3, schk = lane & 7; // stager lane split

  __syncthreads();                       // params ready

  // ---- prologue: corners(0)->set0, pack->Ald[0]; B(0)->Bld[0]; corners(1)->set1
  short8 c00, c01, c02, c03, c10, c11, c12, c13;
  float4 wt0, wt1;
  if (samp) {
    intx4 coff = sOff[sm];
    wt0 = sWt[sm];
    int cbeg = scg << 3;                 // step0: t=0, cc=0
    c00 = *(const short8*)(xb + coff.x + cbeg);
    c01 = *(const short8*)(xb + coff.y + cbeg);
    c02 = *(const short8*)(xb + coff.z + cbeg);
    c03 = *(const short8*)(xb + coff.w + cbeg);
  } else {
#pragma unroll
    for (int it = 0; it < 4; ++it) {
      int rb = wsid * 32 + it * 8;
      int r  = rb + srow;
      const unsigned short* g = Bw + (size_t)r * KTOT + ((schk ^ (r & 7)) << 3);
      load_lds16(g, &Bld[0][rb * 64]);
    }
  }
  if (samp) {
    short8 pk;
#pragma unroll
    for (int j = 0; j < 8; ++j) {
      float v = wt0.x * b2f((unsigned short)c00[j]) +
                wt0.y * b2f((unsigned short)c01[j]) +
                wt0.z * b2f((unsigned short)c02[j]) +
                wt0.w * b2f((unsigned short)c03[j]);
      pk[j] = (short)f2bf(v);
    }
    *(short8*)&Ald[0][sm * 64 + ((scg ^ (sm & 7)) << 3)] = pk;
    // corners(1): t=0, cc=1
    intx4 coff = sOff[sm];
    wt1 = sWt[sm];
    int cbeg = 64 + (scg << 3);
    c10 = *(const short8*)(xb + coff.x + cbeg);
    c11 = *(const short8*)(xb + coff.y + cbeg);
    c12 = *(const short8*)(xb + coff.z + cbeg);
    c13 = *(const short8*)(xb + coff.w + cbeg);
  }
  __syncthreads();                       // buf0 ready, corners(1) in regs

#define FUSED_STEP(S, CUR, PC0, PC1, PC2, PC3, PWT, LC0, LC1, LC2, LC3, LWT)   \
  {                                                                            \
    if ((S) < 35) {                                                            \
      if (samp) {                                                              \
        short8 pk;                                                             \
        _Pragma("unroll")                                                      \
        for (int j = 0; j < 8; ++j) {                                          \
          float v = PWT.x * b2f((unsigned short)PC0[j]) +                      \
                    PWT.y * b2f((unsigned short)PC1[j]) +                      \
                    PWT.z * b2f((unsigned short)PC2[j]) +                      \
                    PWT.w * b2f((unsigned short)PC3[j]);                       \
          pk[j] = (short)f2bf(v);                                              \
        }                                                                      \
        *(short8*)&Ald[(CUR) ^ 1][sm * 64 + ((scg ^ (sm & 7)) << 3)] = pk;     \
      } else {                                                                 \
        int ns  = (S) + 1;                                                     \
        int tkc = ((ns >> 2) << 8) + ((ns & 3) << 6);                          \
        _Pragma("unroll")                                                      \
        for (int it = 0; it < 4; ++it) {                                       \
          int rb = wsid * 32 + it * 8;                                         \
          int r  = rb + srow;                                                  \
          const unsigned short* g =                                            \
              Bw + (size_t)r * KTOT + tkc + ((schk ^ (r & 7)) << 3);           \
          load_lds16(g, &Bld[(CUR) ^ 1][rb * 64]);                             \
        }                                                                      \
      }                                                                        \
    }                                                                          \
    if (samp && (S) < 34) {                                                    \
      int ns2 = (S) + 2;                                                       \
      intx4 coff = sOff[(ns2 >> 2) * 64 + sm];                                 \
      LWT = sWt[(ns2 >> 2) * 64 + sm];                                         \
      int cbeg = ((ns2 & 3) << 6) + (scg << 3);                                \
      LC0 = *(const short8*)(xb + coff.x + cbeg);                              \
      LC1 = *(const short8*)(xb + coff.y + cbeg);                              \
      LC2 = *(const short8*)(xb + coff.z + cbeg);                              \
      LC3 = *(const short8*)(xb + coff.w + cbeg);                              \
    }                                                                          \
    _Pragma("unroll")                                                          \
    for (int ks = 0; ks < 2; ++ks) {                                           \
      int cbase = ks * 4 + quad;                                               \
      int ra = qm * 16 + l15;                                                  \
      short8 a = *(short8*)&Ald[CUR][ra * 64 + ((cbase ^ (ra & 7)) << 3)];     \
      _Pragma("unroll")                                                        \
      for (int nj = 0; nj < 4; ++nj) {                                         \
        int rb2 = qn * 64 + nj * 16 + l15;                                     \
        short8 b = *(short8*)&Bld[CUR][rb2 * 64 + ((cbase ^ (rb2 & 7)) << 3)]; \
        acc[nj] = __builtin_amdgcn_mfma_f32_16x16x32_bf16(a, b, acc[nj], 0, 0, 0); \
      }                                                                        \
    }                                                                          \
    __syncthreads();                                                           \
  }

  for (int ss = 0; ss < 36; ss += 2) {
    FUSED_STEP(ss,     0, c10, c11, c12, c13, wt1, c00, c01, c02, c03, wt0);
    FUSED_STEP(ss + 1, 1, c00, c01, c02, c03, wt0, c10, c11, c12, c13, wt1);
  }
#undef FUSED_STEP

  // ---- epilogue ----
  int m0 = M0 + qm * 16 + quad * 4;
  int img2 = m0 >> 12, hw = m0 & 4095;
#pragma unroll
  for (int nj = 0; nj < 4; ++nj) {
    int oc = qn * 64 + nj * 16 + l15;
    float4 vv = make_float4(acc[nj][0], acc[nj][1], acc[nj][2], acc[nj][3]);
    *(float4*)&out[((size_t)img2 * OUTC + oc) * HWSZ + hw] = vv;
  }
}

// ===========================================================================
// FALLBACK PATH (round-2 fused kernels) — only if ws is too small.
// ===========================================================================
__global__ __launch_bounds__(256) void conv_offset_kernel(
    const float* __restrict__ x, const unsigned short* __restrict__ B2w,
    const float* __restrict__ ob, float* __restrict__ om) {
  __shared__ unsigned short A_lds[64 * 40];
  __shared__ unsigned short B_lds[32 * 40];
  int bid = blockIdx.x;
  int n = bid >> 6, h = bid & 63;
  int tid = threadIdx.x, lane = tid & 63, q = tid >> 6;
  const float* xn = x + n * (CIN * HWSZ);
  floatx4 acc0 = {0.f, 0.f, 0.f, 0.f}, acc1 = {0.f, 0.f, 0.f, 0.f};
  int w = tid & 63, cg = tid >> 6, ocb = tid >> 3, part = tid & 7;
  for (int s = 0; s < NSTEPS; ++s) {
    int t = s >> 3, c0 = (s & 7) << 5;
    int dy = t / 3 - 1, dx = t % 3 - 1;
    __syncthreads();
    {
      int y = h + dy, xx = w + dx;
      bool inb = ((unsigned)y < 64u) && ((unsigned)xx < 64u);
      const float* xb = xn + (c0 + cg * 8) * HWSZ + y * 64 + xx;
      short8 pk;
#pragma unroll
      for (int j = 0; j < 8; ++j) { float v = inb ? xb[j * HWSZ] : 0.0f; pk[j] = (short)f2bf(v); }
      *(short8*)&A_lds[w * 40 + cg * 8] = pk;
    }
    { const unsigned short* bp = B2w + ocb * KTOT + (t << 8) + c0 + part * 4;
      *(short4v*)&B_lds[ocb * 40 + part * 4] = *(const short4v*)bp; }
    __syncthreads();
    int fr = (lane >> 4) * 8;
    short8 af  = *(short8*)&A_lds[(q * 16 + (lane & 15)) * 40 + fr];
    short8 bf0 = *(short8*)&B_lds[((lane & 15)) * 40 + fr];
    short8 bf1 = *(short8*)&B_lds[(16 + (lane & 15)) * 40 + fr];
    acc0 = __builtin_amdgcn_mfma_f32_16x16x32_bf16(af, bf0, acc0, 0, 0, 0);
    acc1 = __builtin_amdgcn_mfma_f32_16x16x32_bf16(af, bf1, acc1, 0, 0, 0);
  }
  int g = lane >> 4;
#pragma unroll
  for (int nt = 0; nt < 2; ++nt) {
    floatx4 a = nt ? acc1 : acc0;
    int oc = nt * 16 + (lane & 15);
    if (oc < 27) {
      float bias = ob[oc];
#pragma unroll
      for (int r = 0; r < 4; ++r) {
        int wm = q * 16 + g * 4 + r;
        float val = a[r] + bias;
        if (oc >= 18) val = 1.0f / (1.0f + __expf(-val));
        om[((n * 27 + oc) << 12) + h * 64 + wm] = val;
      }
    }
  }
}

__global__ __launch_bounds__(256) void dcn_main_kernel(
    const float* __restrict__ x, const float* __restrict__ om,
    const unsigned short* __restrict__ Bw, float* __restrict__ out) {
  __shared__ unsigned short A_lds[32 * 40];
  __shared__ unsigned short B_lds[256 * 40];
  __shared__ int    sY[288];
  __shared__ int    sX[288];
  __shared__ float4 sW[288];
  int bid = blockIdx.x;
  int n = bid >> 7, rem = bid & 127, h = rem >> 1, w0 = (rem & 1) << 5;
  int tid = threadIdx.x, lane = tid & 63, q = tid >> 6;
  const float* xn  = x + n * (CIN * HWSZ);
  const float* omn = om + n * (27 * HWSZ);
  for (int v = tid; v < 288; v += 256) {
    int m = v & 31, t = v >> 5;
    int ky = t / 3, kx = t % 3;
    int wg = w0 + m, sp = h * 64 + wg;
    float offy = omn[(2 * t) * HWSZ + sp];
    float offx = omn[(2 * t + 1) * HWSZ + sp];
    float mv   = omn[(18 + t) * HWSZ + sp];
    float him = (float)(h - 1 + ky) + offy;
    float wim = (float)(wg - 1 + kx) + offx;
    float y0f = floorf(him), x0f = floorf(wim);
    float lh = him - y0f, lw = wim - x0f;
    int y0 = (int)y0f, x0i = (int)x0f;
    bool vy0 = (y0 >= 0) && (y0 < HH), vy1 = (y0 + 1 >= 0) && (y0 + 1 < HH);
    bool vx0 = (x0i >= 0) && (x0i < WW), vx1 = (x0i + 1 >= 0) && (x0i + 1 < WW);
    float hh_ = 1.0f - lh, hw_ = 1.0f - lw;
    float4 wt;
    wt.x = (vy0 && vx0) ? hh_ * hw_ * mv : 0.0f;
    wt.y = (vy0 && vx1) ? hh_ * lw  * mv : 0.0f;
    wt.z = (vy1 && vx0) ? lh  * hw_ * mv : 0.0f;
    wt.w = (vy1 && vx1) ? lh  * lw  * mv : 0.0f;
    sY[v] = y0; sX[v] = x0i; sW[v] = wt;
  }
  floatx4 acc[2][4];
#pragma unroll
  for (int mi = 0; mi < 2; ++mi)
#pragma unroll
    for (int nj = 0; nj < 4; ++nj) acc[mi][nj] = (floatx4){0.f, 0.f, 0.f, 0.f};
  int m = tid & 31, cg = tid >> 5, n0 = q * 64;
  for (int s = 0; s < NSTEPS; ++s) {
    int t = s >> 3, c0 = (s & 7) << 5;
    __syncthreads();
    {
      int p = t * 32 + m;
      int y0 = sY[p], x0i = sX[p];
      float4 wt = sW[p];
      int y0c = min(max(y0, 0), 63), y1c = min(max(y0 + 1, 0), 63);
      int x0c = min(max(x0i, 0), 63), x1c = min(max(x0i + 1, 0), 63);
      int i00 = y0c * 64 + x0c, i01 = y0c * 64 + x1c;
      int i10 = y1c * 64 + x0c, i11 = y1c * 64 + x1c;
      const float* xb = xn + (c0 + cg * 4) * HWSZ;
      short4v pk;
#pragma unroll
      for (int j = 0; j < 4; ++j) {
        const float* xc = xb + j * HWSZ;
        float v = wt.x * xc[i00] + wt.y * xc[i01] + wt.z * xc[i10] + wt.w * xc[i11];
        pk[j] = (short)f2bf(v);
      }
      *(short4v*)&A_lds[m * 40 + cg * 4] = pk;
    }
    {
      const short8* bp = (const short8*)(Bw + tid * KTOT + (t << 8) + c0);
      short8 b0 = bp[0], b1 = bp[1], b2 = bp[2], b3 = bp[3];
      short8* dst = (short8*)&B_lds[tid * 40];
      dst[0] = b0; dst[1] = b1; dst[2] = b2; dst[3] = b3;
    }
    __syncthreads();
    int fr = (lane >> 4) * 8;
    short8 a0 = *(short8*)&A_lds[((lane & 15)) * 40 + fr];
    short8 a1 = *(short8*)&A_lds[(16 + (lane & 15)) * 40 + fr];
#pragma unroll
    for (int nj = 0; nj < 4; ++nj) {
      short8 bfp = *(short8*)&B_lds[(n0 + nj * 16 + (lane & 15)) * 40 + fr];
      acc[0][nj] = __builtin_amdgcn_mfma_f32_16x16x32_bf16(a0, bfp, acc[0][nj], 0, 0, 0);
      acc[1][nj] = __builtin_amdgcn_mfma_f32_16x16x32_bf16(a1, bfp, acc[1][nj], 0, 0, 0);
    }
  }
  int g = lane >> 4;
#pragma unroll
  for (int mi = 0; mi < 2; ++mi) {
    int wm = w0 + mi * 16 + g * 4;
#pragma unroll
    for (int nj = 0; nj < 4; ++nj) {
      int oc = n0 + nj * 16 + (lane & 15);
      float4 vv = make_float4(acc[mi][nj][0], acc[mi][nj][1],
                              acc[mi][nj][2], acc[mi][nj][3]);
      *(float4*)&out[((n * OUTC + oc) << 12) + h * 64 + wm] = vv;
    }
  }
}

// ---------------------------------------------------------------------------
extern "C" void kernel_launch(void* const* d_in, const int* in_sizes, int n_in,
                              void* d_out, int out_size, void* d_ws, size_t ws_size,
                              hipStream_t stream) {
  const float* x     = (const float*)d_in[0];
  const float* offw  = (const float*)d_in[1];
  const float* ob    = (const float*)d_in[2];
  const float* dcn_w = (const float*)d_in[3];
  float* out = (float*)d_out;

  unsigned short* Bw  = (unsigned short*)((char*)d_ws + WS_BW_OFF);
  unsigned short* B2w = (unsigned short*)((char*)d_ws + WS_B2W_OFF);
  float*          omb = (float*)((char*)d_ws + WS_OM_OFF);
  unsigned short* xtb = (unsigned short*)((char*)d_ws + WS_XT_OFF);

  if (ws_size >= (size_t)WS_END) {
    // main path: 3 launches, no A materialization
    prep_xpose_kernel<<<512, 256, 0, stream>>>(dcn_w, offw, x, Bw, B2w, xtb);
    conv_offset_stream<<<MTOT / 32, 256, 0, stream>>>(xtb, B2w, omb);
    dcn_fused_kernel<<<256, 1024, 0, stream>>>(xtb, omb, ob, Bw, out);
  } else {
    // fallback: round-2 fused kernels (needs only ~3.1 MB of ws)
    prep_xpose_kernel<<<256, 256, 0, stream>>>(dcn_w, offw, x, Bw, B2w, xtb);
    conv_offset_kernel<<<NB * HH, 256, 0, stream>>>(x, B2w, ob, omb);
    dcn_main_kernel<<<NB * HH * 2, 256, 0, stream>>>(x, omb, Bw, out);
  }
}

// Round 8
// 134.927 us; speedup vs baseline: 1.2244x; 1.1809x over previous
//
#include <hip/hip_runtime.h>
#include <hip/hip_bf16.h>
#include <math.h>

// Problem constants (N, C, H, W) = (4, 256, 64, 64), out_C = 256, FS=3, pad=1, stride=1
#define NB     4
#define CIN    256
#define HH     64
#define WW     64
#define OUTC   256
#define K2     9
#define KTOT   2304                // CIN * K2
#define HWSZ   4096                // HH * WW
#define NSTEPS 72                  // KTOT / 32
#define MTOT   16384               // NB * HWSZ

// K ordering everywhere: k' = tap*256 + c (tap-major).

typedef __attribute__((ext_vector_type(4)))  float  floatx4;
typedef __attribute__((ext_vector_type(16))) float  floatx16;
typedef __attribute__((ext_vector_type(8)))  short  short8;
typedef __attribute__((ext_vector_type(4)))  short  short4v;
typedef __attribute__((ext_vector_type(4)))  int    intx4;

__device__ __forceinline__ unsigned short f2bf(float f) {
  union { float f; unsigned u; } v; v.f = f;
  unsigned r = v.u + 0x7FFF + ((v.u >> 16) & 1);   // round-to-nearest-even
  return (unsigned short)(r >> 16);
}
__device__ __forceinline__ float b2f(unsigned short s) {
  union { unsigned u; float f; } v; v.u = ((unsigned)s) << 16;
  return v.f;
}

// ---------------------------------------------------------------------------
// MAIN-PATH workspace (bytes):
//   Bfrag  : [144 s16][8 nt][64 lane][8 bf16]  = 1,179,648  (32x32x16 frag order)
//   B2frag : [72 s32][2 nt][64 lane][8 bf16]   =   147,456  (16x16x32 frag order)
//   xt     : [4][64][64][256] bf16             = 8,388,608  (channel-last x)
#define WSM_BFRAG   0
#define WSM_B2FRAG  1179648
#define WSM_XT      (1179648 + 147456)
#define WSM_END     (WSM_XT + NB * HWSZ * CIN * 2)
// FALLBACK workspace (round-2 path, only if ws is tiny):
#define WSF_BW      0
#define WSF_B2W     (KTOT * OUTC * 2)
#define WSF_OM      (WSF_B2W + KTOT * 32 * 2)
#define WSF_END     (WSF_OM + NB * 27 * HWSZ * 4)

// ---------------------------------------------------------------------------
// Kernel 0 (main): xpose (blocks 0..255) + Bfrag pack (256..543) + B2frag
// pack (544..579).
// ---------------------------------------------------------------------------
__global__ __launch_bounds__(256) void prep_main_kernel(
    const float* __restrict__ dcn_w, const float* __restrict__ offw,
    const float* __restrict__ x,
    unsigned short* __restrict__ Bfrag, unsigned short* __restrict__ B2frag,
    unsigned short* __restrict__ xt) {
  int bid = blockIdx.x;
  int tid = threadIdx.x;
  if (bid < 256) {
    __shared__ unsigned short T[64 * 266];   // [w][c], pad 266
    int img = bid >> 6, h = bid & 63;
    const float* xp = x + (size_t)img * CIN * HWSZ + h * 64;
    int w = tid & 63, cq = tid >> 6;
    for (int cb = 0; cb < 256; cb += 4) {
      int c = cb + cq;
      T[w * 266 + c] = f2bf(xp[(size_t)c * HWSZ + w]);   // lanes=w: coalesced
    }
    __syncthreads();
    int w2 = tid >> 2, cg = (tid & 3) << 6;
    unsigned short* o = xt + ((size_t)(img * 64 + h) * 64 + w2) * 256 + cg;
#pragma unroll
    for (int i = 0; i < 64; i += 8) {
      short8 v = *(short8*)&T[w2 * 266 + cg + i];
      *(short8*)(o + i) = v;
    }
  } else if (bid < 544) {
    // Bfrag: e in [0, 73728): lane=e&63, nt=(e>>6)&7, s16=e>>9
    int e = (bid - 256) * 256 + tid;
    int lane = e & 63, nt = (e >> 6) & 7, s16 = e >> 9;
    int n = nt * 32 + (lane & 31);
    int kb = s16 * 16 + ((lane >> 5) << 3);
    short8 pk;
#pragma unroll
    for (int j = 0; j < 8; ++j) {
      int k = kb + j;
      pk[j] = (short)f2bf(dcn_w[n * KTOT + (k & 255) * 9 + (k >> 8)]);
    }
    *(short8*)(Bfrag + (size_t)e * 8) = pk;
  } else {
    // B2frag: e in [0, 9216): lane=e&63, nt=(e>>6)&1, s32=e>>7
    int e = (bid - 544) * 256 + tid;
    int lane = e & 63, nt = (e >> 6) & 1, s32 = e >> 7;
    int n = nt * 16 + (lane & 15);
    int kb = s32 * 32 + ((lane >> 4) << 3);
    short8 pk;
#pragma unroll
    for (int j = 0; j < 8; ++j) {
      int k = kb + j;
      pk[j] = (n < 27) ? (short)f2bf(offw[n * KTOT + (k & 255) * 9 + (k >> 8)])
                       : (short)0;
    }
    *(short8*)(B2frag + (size_t)e * 8) = pk;
  }
}

// ---------------------------------------------------------------------------
// Kernel 1 (main): FULLY FUSED offset-conv + sampling + GEMM, v4.
// Block = one (img,h) row: M=64, N=256 (sample-once), K=2304. Grid 256,
// 256 thr (4 waves, 1/SIMD, big tiles).
// Phase A (prologue): offset conv as K-split MFMA (wave q does steps q+4i),
//   partials -> LDS -> bilinear params in LDS.
// Phase B (36 K64-steps): wave tile 64m x 64oc via 32x32x16 MFMA (4 accs,
//   16 MFMA/step). A sampled to LDS in frag order (dbuf, ds_write_b128);
//   B read from frag-packed GLOBAL straight to regs (prefetch 1 step) -> the
//   per-step barrier orders only LDS writes; no vmcnt drain.
// ---------------------------------------------------------------------------
__global__ __launch_bounds__(256, 1) void dcn_fused_kernel(
    const unsigned short* __restrict__ xt,
    const unsigned short* __restrict__ Bfrag,
    const unsigned short* __restrict__ B2frag,
    const float* __restrict__ ob, float* __restrict__ out) {
  __shared__ unsigned short Ald[2][8][64][8];   // 16 KB, frag order
  __shared__ intx4  sOff[576];                  //  9 KB
  __shared__ float4 sWt[576];                   //  9 KB
  __shared__ float  omp[4 * 32 * 68];           // 34.8 KB conv partials

  int bid = blockIdx.x;                 // 0..255 = (img,h)
  int img = bid >> 6, h = bid & 63;
  const unsigned short* xb = xt + (size_t)img * HWSZ * 256;

  int tid  = threadIdx.x;
  int lane = tid & 63, q = tid >> 6;    // 4 waves
  int quad = lane >> 4, l15 = lane & 15;
  int l31  = lane & 31,  lh = lane >> 5;

  // ================= Phase A: offset conv (K-split over waves) ==============
  {
    floatx4 cacc[4][2];
#pragma unroll
    for (int mt = 0; mt < 4; ++mt)
#pragma unroll
      for (int nt = 0; nt < 2; ++nt) cacc[mt][nt] = (floatx4){0.f, 0.f, 0.f, 0.f};
    short8 cpa[2][4];
    short8 cpb[2][2];

#define CONV_LOAD(I, SLOT)                                                     \
  {                                                                            \
    int s = q + (I) * 4;                                                       \
    int t = s >> 3;                                                            \
    int dy = t / 3 - 1, dx = t % 3 - 1;                                        \
    int y = h + dy;                                                            \
    int cb0 = ((s & 7) << 5) + (quad << 3);                                    \
    _Pragma("unroll")                                                          \
    for (int mt = 0; mt < 4; ++mt) {                                           \
      int xx = mt * 16 + l15 + dx;                                             \
      short8 v = {0, 0, 0, 0, 0, 0, 0, 0};                                     \
      if (((unsigned)y < 64u) && ((unsigned)xx < 64u))                         \
        v = *(const short8*)(xb + ((y * 64 + xx) << 8) + cb0);                 \
      cpa[SLOT][mt] = v;                                                       \
    }                                                                          \
    _Pragma("unroll")                                                          \
    for (int nt = 0; nt < 2; ++nt)                                             \
      cpb[SLOT][nt] = *(const short8*)(B2frag + (((s * 2 + nt) * 64 + lane) << 3)); \
  }

    CONV_LOAD(0, 0);
#pragma unroll 2
    for (int i = 0; i < 18; ++i) {
      int sl = i & 1;
      if (i < 17) CONV_LOAD(i + 1, sl ^ 1);
#pragma unroll
      for (int mt = 0; mt < 4; ++mt)
#pragma unroll
        for (int nt = 0; nt < 2; ++nt)
          cacc[mt][nt] = __builtin_amdgcn_mfma_f32_16x16x32_bf16(
              cpa[sl][mt], cpb[sl][nt], cacc[mt][nt], 0, 0, 0);
    }
#undef CONV_LOAD
    // partials: omp[q][oc][m], stride 68 (16B-aligned, conflict-light)
#pragma unroll
    for (int mt = 0; mt < 4; ++mt)
#pragma unroll
      for (int nt = 0; nt < 2; ++nt) {
        int oc = nt * 16 + l15;
        float4 vv = make_float4(cacc[mt][nt][0], cacc[mt][nt][1],
                                cacc[mt][nt][2], cacc[mt][nt][3]);
        *(float4*)&omp[(q * 32 + oc) * 68 + mt * 16 + quad * 4] = vv;
      }
  }
  __syncthreads();

  // ---- bilinear params: 9 taps x 64 w (sum the 4 K-partials + bias) ----
  for (int v = tid; v < 576; v += 256) {
    int w = v & 63, t = v >> 6;
    int ky = t / 3, kx = t % 3;
    float offy = omp[(0 * 32 + 2 * t) * 68 + w] + omp[(1 * 32 + 2 * t) * 68 + w] +
                 omp[(2 * 32 + 2 * t) * 68 + w] + omp[(3 * 32 + 2 * t) * 68 + w] +
                 ob[2 * t];
    float offx = omp[(0 * 32 + 2 * t + 1) * 68 + w] + omp[(1 * 32 + 2 * t + 1) * 68 + w] +
                 omp[(2 * 32 + 2 * t + 1) * 68 + w] + omp[(3 * 32 + 2 * t + 1) * 68 + w] +
                 ob[2 * t + 1];
    float mraw = omp[(0 * 32 + 18 + t) * 68 + w] + omp[(1 * 32 + 18 + t) * 68 + w] +
                 omp[(2 * 32 + 18 + t) * 68 + w] + omp[(3 * 32 + 18 + t) * 68 + w] +
                 ob[18 + t];
    float mv   = 1.0f / (1.0f + __expf(-mraw));
    float him  = (float)(h - 1 + ky) + offy;
    float wim  = (float)(w - 1 + kx) + offx;
    float y0f = floorf(him), x0f = floorf(wim);
    float lhf = him - y0f, lwf = wim - x0f;
    int y0 = (int)y0f, x0i = (int)x0f;
    bool vy0 = (y0 >= 0) && (y0 < HH);
    bool vy1 = (y0 + 1 >= 0) && (y0 + 1 < HH);
    bool vx0 = (x0i >= 0) && (x0i < WW);
    bool vx1 = (x0i + 1 >= 0) && (x0i + 1 < WW);
    float hh_ = 1.0f - lhf, hw_ = 1.0f - lwf;
    float4 wt;
    wt.x = (vy0 && vx0) ? hh_ * hw_ * mv : 0.0f;
    wt.y = (vy0 && vx1) ? hh_ * lwf * mv : 0.0f;
    wt.z = (vy1 && vx0) ? lhf * hw_ * mv : 0.0f;
    wt.w = (vy1 && vx1) ? lhf * lwf * mv : 0.0f;
    int y0c = min(max(y0, 0), 63), y1c = min(max(y0 + 1, 0), 63);
    int x0c = min(max(x0i, 0), 63), x1c = min(max(x0i + 1, 0), 63);
    intx4 ii = {(y0c * 64 + x0c) << 8, (y0c * 64 + x1c) << 8,
                (y1c * 64 + x0c) << 8, (y1c * 64 + x1c) << 8};
    sOff[v] = ii;
    sWt[v]  = wt;
  }
  __syncthreads();

  // ================= Phase B: fused sampling + GEMM ========================
  floatx16 acc[2][2];
#pragma unroll
  for (int mt = 0; mt < 2; ++mt)
#pragma unroll
    for (int nt = 0; nt < 2; ++nt)
#pragma unroll
      for (int e = 0; e < 16; ++e) acc[mt][nt][e] = 0.f;

  int m   = tid >> 2;          // sampler m row (0..63)
  int ch0 = tid & 3;           // chunk pair {ch0, ch0+4}
  int mtm = m >> 5, m31 = m & 31;

  short8 bfr[2][8];            // B frags, ping-pong [s&1][sub*2+nt]
  short8 cr[2][4];             // corner regs [chunk-slot][corner]
  float4 pwt;

  // ---- prologue: b(0), corners(0), pack(0), corners(1) ----
#pragma unroll
  for (int sub = 0; sub < 4; ++sub)
#pragma unroll
    for (int nt = 0; nt < 2; ++nt)
      bfr[0][sub * 2 + nt] = *(const short8*)(
          Bfrag + (((size_t)sub * 8 + (q * 2 + nt)) * 64 + lane) * 8);
  {
    intx4 off = sOff[m];
    pwt = sWt[m];
    int cb = ch0 * 8;
#pragma unroll
    for (int sl = 0; sl < 2; ++sl) {
      int cc = cb + sl * 32;
      cr[sl][0] = *(const short8*)(xb + off.x + cc);
      cr[sl][1] = *(const short8*)(xb + off.y + cc);
      cr[sl][2] = *(const short8*)(xb + off.z + cc);
      cr[sl][3] = *(const short8*)(xb + off.w + cc);
    }
  }
#pragma unroll
  for (int sl = 0; sl < 2; ++sl) {
    int ch = ch0 + sl * 4;
    short8 pk;
#pragma unroll
    for (int j = 0; j < 8; ++j) {
      float v = pwt.x * b2f((unsigned short)cr[sl][0][j]) +
                pwt.y * b2f((unsigned short)cr[sl][1][j]) +
                pwt.z * b2f((unsigned short)cr[sl][2][j]) +
                pwt.w * b2f((unsigned short)cr[sl][3][j]);
      pk[j] = (short)f2bf(v);
    }
    *(short8*)&Ald[0][(ch >> 1) * 2 + mtm][(ch & 1) * 32 + m31][0] = pk;
  }
  {
    // corners for s=1 (t=0, cq=1)
    intx4 off = sOff[m];
    pwt = sWt[m];
    int cb = 64 + ch0 * 8;
#pragma unroll
    for (int sl = 0; sl < 2; ++sl) {
      int cc = cb + sl * 32;
      cr[sl][0] = *(const short8*)(xb + off.x + cc);
      cr[sl][1] = *(const short8*)(xb + off.y + cc);
      cr[sl][2] = *(const short8*)(xb + off.z + cc);
      cr[sl][3] = *(const short8*)(xb + off.w + cc);
    }
  }
  __syncthreads();

  // ---- main loop: 36 K64-steps ----
#pragma unroll 2
  for (int s = 0; s < 36; ++s) {
    int cur = s & 1;
    // B frags for s+1 -> other buffer (register loads; no barrier coupling)
    if (s < 35) {
      int s16b = (s + 1) * 4;
#pragma unroll
      for (int sub = 0; sub < 4; ++sub)
#pragma unroll
        for (int nt = 0; nt < 2; ++nt)
          bfr[cur ^ 1][sub * 2 + nt] = *(const short8*)(
              Bfrag + (((size_t)(s16b + sub) * 8 + (q * 2 + nt)) * 64 + lane) * 8);
    }
    // pack corners(s+1) -> Ald[cur^1]
    if (s < 35) {
#pragma unroll
      for (int sl = 0; sl < 2; ++sl) {
        int ch = ch0 + sl * 4;
        short8 pk;
#pragma unroll
        for (int j = 0; j < 8; ++j) {
          float v = pwt.x * b2f((unsigned short)cr[sl][0][j]) +
                    pwt.y * b2f((unsigned short)cr[sl][1][j]) +
                    pwt.z * b2f((unsigned short)cr[sl][2][j]) +
                    pwt.w * b2f((unsigned short)cr[sl][3][j]);
          pk[j] = (short)f2bf(v);
        }
        *(short8*)&Ald[cur ^ 1][(ch >> 1) * 2 + mtm][(ch & 1) * 32 + m31][0] = pk;
      }
    }
    // corner loads for s+2 (latency covered by this step's MFMA + next pack)
    if (s < 34) {
      int s2 = s + 2;
      int t2 = s2 >> 2;
      intx4 off = sOff[t2 * 64 + m];
      pwt = sWt[t2 * 64 + m];
      int cb = (s2 & 3) * 64 + ch0 * 8;
#pragma unroll
      for (int sl = 0; sl < 2; ++sl) {
        int cc = cb + sl * 32;
        cr[sl][0] = *(const short8*)(xb + off.x + cc);
        cr[sl][1] = *(const short8*)(xb + off.y + cc);
        cr[sl][2] = *(const short8*)(xb + off.z + cc);
        cr[sl][3] = *(const short8*)(xb + off.w + cc);
      }
    }
    // 16 MFMA (32x32x16), A from LDS frag order (conflict-free b128)
#pragma unroll
    for (int sub = 0; sub < 4; ++sub) {
      short8 a0 = *(short8*)&Ald[cur][sub * 2 + 0][lane][0];
      short8 a1 = *(short8*)&Ald[cur][sub * 2 + 1][lane][0];
#pragma unroll
      for (int nt = 0; nt < 2; ++nt) {
        acc[0][nt] = __builtin_amdgcn_mfma_f32_32x32x16_bf16(
            a0, bfr[cur][sub * 2 + nt], acc[0][nt], 0, 0, 0);
        acc[1][nt] = __builtin_amdgcn_mfma_f32_32x32x16_bf16(
            a1, bfr[cur][sub * 2 + nt], acc[1][nt], 0, 0, 0);
      }
    }
    __syncthreads();   // orders only ds_writes (lgkm) — B is register-loaded
  }

  // ---- epilogue: D col = oc (lane&31), row = (r&3)+8*(r>>2)+4*(lane>>5) ----
#pragma unroll
  for (int mt = 0; mt < 2; ++mt)
#pragma unroll
    for (int nt = 0; nt < 2; ++nt) {
      int oc = q * 64 + nt * 32 + l31;
      float* obase = out + (((size_t)img * OUTC + oc) << 12) + h * 64 +
                     mt * 32 + lh * 4;
#pragma unroll
      for (int rg = 0; rg < 4; ++rg) {
        float4 vv = make_float4(acc[mt][nt][rg * 4 + 0], acc[mt][nt][rg * 4 + 1],
                                acc[mt][nt][rg * 4 + 2], acc[mt][nt][rg * 4 + 3]);
        *(float4*)(obase + rg * 8) = vv;
      }
    }
}

// ===========================================================================
// FALLBACK PATH (round-2 kernels) — only if ws is too small (< ~9.7 MB).
// ===========================================================================
__global__ __launch_bounds__(256) void prep_fb_kernel(
    const float* __restrict__ dcn_w, const float* __restrict__ offw,
    unsigned short* __restrict__ Bw, unsigned short* __restrict__ B2w) {
  int oc = blockIdx.x;
  for (int k = threadIdx.x; k < KTOT; k += 256) {
    int t = k >> 8, c = k & 255;
    Bw[oc * KTOT + k] = f2bf(dcn_w[oc * KTOT + c * 9 + t]);
    if (oc < 32)
      B2w[oc * KTOT + k] = (oc < 27) ? f2bf(offw[oc * KTOT + c * 9 + t])
                                     : (unsigned short)0;
  }
}

__global__ __launch_bounds__(256) void conv_offset_kernel(
    const float* __restrict__ x, const unsigned short* __restrict__ B2w,
    const float* __restrict__ ob, float* __restrict__ om) {
  __shared__ unsigned short A_lds[64 * 40];
  __shared__ unsigned short B_lds[32 * 40];
  int bid = blockIdx.x;
  int n = bid >> 6, h = bid & 63;
  int tid = threadIdx.x, lane = tid & 63, q = tid >> 6;
  const float* xn = x + n * (CIN * HWSZ);
  floatx4 acc0 = {0.f, 0.f, 0.f, 0.f}, acc1 = {0.f, 0.f, 0.f, 0.f};
  int w = tid & 63, cg = tid >> 6, ocb = tid >> 3, part = tid & 7;
  for (int s = 0; s < NSTEPS; ++s) {
    int t = s >> 3, c0 = (s & 7) << 5;
    int dy = t / 3 - 1, dx = t % 3 - 1;
    __syncthreads();
    {
      int y = h + dy, xx = w + dx;
      bool inb = ((unsigned)y < 64u) && ((unsigned)xx < 64u);
      const float* xb = xn + (c0 + cg * 8) * HWSZ + y * 64 + xx;
      short8 pk;
#pragma unroll
      for (int j = 0; j < 8; ++j) { float v = inb ? xb[j * HWSZ] : 0.0f; pk[j] = (short)f2bf(v); }
      *(short8*)&A_lds[w * 40 + cg * 8] = pk;
    }
    { const unsigned short* bp = B2w + ocb * KTOT + (t << 8) + c0 + part * 4;
      *(short4v*)&B_lds[ocb * 40 + part * 4] = *(const short4v*)bp; }
    __syncthreads();
    int fr = (lane >> 4) * 8;
    short8 af  = *(short8*)&A_lds[(q * 16 + (lane & 15)) * 40 + fr];
    short8 bf0 = *(short8*)&B_lds[((lane & 15)) * 40 + fr];
    short8 bf1 = *(short8*)&B_lds[(16 + (lane & 15)) * 40 + fr];
    acc0 = __builtin_amdgcn_mfma_f32_16x16x32_bf16(af, bf0, acc0, 0, 0, 0);
    acc1 = __builtin_amdgcn_mfma_f32_16x16x32_bf16(af, bf1, acc1, 0, 0, 0);
  }
  int g = lane >> 4;
#pragma unroll
  for (int nt = 0; nt < 2; ++nt) {
    floatx4 a = nt ? acc1 : acc0;
    int oc = nt * 16 + (lane & 15);
    if (oc < 27) {
      float bias = ob[oc];
#pragma unroll
      for (int r = 0; r < 4; ++r) {
        int wm = q * 16 + g * 4 + r;
        float val = a[r] + bias;
        if (oc >= 18) val = 1.0f / (1.0f + __expf(-val));
        om[((n * 27 + oc) << 12) + h * 64 + wm] = val;
      }
    }
  }
}

__global__ __launch_bounds__(256) void dcn_main_kernel(
    const float* __restrict__ x, const float* __restrict__ om,
    const unsigned short* __restrict__ Bw, float* __restrict__ out) {
  __shared__ unsigned short A_lds[32 * 40];
  __shared__ unsigned short B_lds[256 * 40];
  __shared__ int    sY[288];
  __shared__ int    sX[288];
  __shared__ float4 sW[288];
  int bid = blockIdx.x;
  int n = bid >> 7, rem = bid & 127, h = rem >> 1, w0 = (rem & 1) << 5;
  int tid = threadIdx.x, lane = tid & 63, q = tid >> 6;
  const float* xn  = x + n * (CIN * HWSZ);
  const float* omn = om + n * (27 * HWSZ);
  for (int v = tid; v < 288; v += 256) {
    int m = v & 31, t = v >> 5;
    int ky = t / 3, kx = t % 3;
    int wg = w0 + m, sp = h * 64 + wg;
    float offy = omn[(2 * t) * HWSZ + sp];
    float offx = omn[(2 * t + 1) * HWSZ + sp];
    float mv   = omn[(18 + t) * HWSZ + sp];
    float him = (float)(h - 1 + ky) + offy;
    float wim = (float)(wg - 1 + kx) + offx;
    float y0f = floorf(him), x0f = floorf(wim);
    float lh = him - y0f, lw = wim - x0f;
    int y0 = (int)y0f, x0i = (int)x0f;
    bool vy0 = (y0 >= 0) && (y0 < HH), vy1 = (y0 + 1 >= 0) && (y0 + 1 < HH);
    bool vx0 = (x0i >= 0) && (x0i < WW), vx1 = (x0i + 1 >= 0) && (x0i + 1 < WW);
    float hh_ = 1.0f - lh, hw_ = 1.0f - lw;
    float4 wt;
    wt.x = (vy0 && vx0) ? hh_ * hw_ * mv : 0.0f;
    wt.y = (vy0 && vx1) ? hh_ * lw  * mv : 0.0f;
    wt.z = (vy1 && vx0) ? lh  * hw_ * mv : 0.0f;
    wt.w = (vy1 && vx1) ? lh  * lw  * mv : 0.0f;
    sY[v] = y0; sX[v] = x0i; sW[v] = wt;
  }
  floatx4 acc[2][4];
#pragma unroll
  for (int mi = 0; mi < 2; ++mi)
#pragma unroll
    for (int nj = 0; nj < 4; ++nj) acc[mi][nj] = (floatx4){0.f, 0.f, 0.f, 0.f};
  int m = tid & 31, cg = tid >> 5, n0 = q * 64;
  for (int s = 0; s < NSTEPS; ++s) {
    int t = s >> 3, c0 = (s & 7) << 5;
    __syncthreads();
    {
      int p = t * 32 + m;
      int y0 = sY[p], x0i = sX[p];
      float4 wt = sW[p];
      int y0c = min(max(y0, 0), 63), y1c = min(max(y0 + 1, 0), 63);
      int x0c = min(max(x0i, 0), 63), x1c = min(max(x0i + 1, 0), 63);
      int i00 = y0c * 64 + x0c, i01 = y0c * 64 + x1c;
      int i10 = y1c * 64 + x0c, i11 = y1c * 64 + x1c;
      const float* xb = xn + (c0 + cg * 4) * HWSZ;
      short4v pk;
#pragma unroll
      for (int j = 0; j < 4; ++j) {
        const float* xc = xb + j * HWSZ;
        float v = wt.x * xc[i00] + wt.y * xc[i01] + wt.z * xc[i10] + wt.w * xc[i11];
        pk[j] = (short)f2bf(v);
      }
      *(short4v*)&A_lds[m * 40 + cg * 4] = pk;
    }
    {
      const short8* bp = (const short8*)(Bw + tid * KTOT + (t << 8) + c0);
      short8 b0 = bp[0], b1 = bp[1], b2 = bp[2], b3 = bp[3];
      short8* dst = (short8*)&B_lds[tid * 40];
      dst[0] = b0; dst[1] = b1; dst[2] = b2; dst[3] = b3;
    }
    __syncthreads();
    int fr = (lane >> 4) * 8;
    short8 a0 = *(short8*)&A_lds[((lane & 15)) * 40 + fr];
    short8 a1 = *(short8*)&A_lds[(16 + (lane & 15)) * 40 + fr];
#pragma unroll
    for (int nj = 0; nj < 4; ++nj) {
      short8 bfp = *(short8*)&B_lds[(n0 + nj * 16 + (lane & 15)) * 40 + fr];
      acc[0][nj] = __builtin_amdgcn_mfma_f32_16x16x32_bf16(a0, bfp, acc[0][nj], 0, 0, 0);
      acc[1][nj] = __builtin_amdgcn_mfma_f32_16x16x32_bf16(a1, bfp, acc[1][nj], 0, 0, 0);
    }
  }
  int g = lane >> 4;
#pragma unroll
  for (int mi = 0; mi < 2; ++mi) {
    int wm = w0 + mi * 16 + g * 4;
#pragma unroll
    for (int nj = 0; nj < 4; ++nj) {
      int oc = n0 + nj * 16 + (lane & 15);
      float4 vv = make_float4(acc[mi][nj][0], acc[mi][nj][1],
                              acc[mi][nj][2], acc[mi][nj][3]);
      *(float4*)&out[((n * OUTC + oc) << 12) + h * 64 + wm] = vv;
    }
  }
}

// ---------------------------------------------------------------------------
extern "C" void kernel_launch(void* const* d_in, const int* in_sizes, int n_in,
                              void* d_out, int out_size, void* d_ws, size_t ws_size,
                              hipStream_t stream) {
  const float* x     = (const float*)d_in[0];
  const float* offw  = (const float*)d_in[1];
  const float* ob    = (const float*)d_in[2];
  const float* dcn_w = (const float*)d_in[3];
  float* out = (float*)d_out;

  if (ws_size >= (size_t)WSM_END) {
    unsigned short* Bfrag  = (unsigned short*)((char*)d_ws + WSM_BFRAG);
    unsigned short* B2frag = (unsigned short*)((char*)d_ws + WSM_B2FRAG);
    unsigned short* xtb    = (unsigned short*)((char*)d_ws + WSM_XT);
    // main path: 2 launches total
    prep_main_kernel<<<580, 256, 0, stream>>>(dcn_w, offw, x, Bfrag, B2frag, xtb);
    dcn_fused_kernel<<<256, 256, 0, stream>>>(xtb, Bfrag, B2frag, ob, out);
  } else {
    unsigned short* Bw  = (unsigned short*)((char*)d_ws + WSF_BW);
    unsigned short* B2w = (unsigned short*)((char*)d_ws + WSF_B2W);
    float*          omb = (float*)((char*)d_ws + WSF_OM);
    prep_fb_kernel<<<256, 256, 0, stream>>>(dcn_w, offw, Bw, B2w);
    conv_offset_kernel<<<NB * HH, 256, 0, stream>>>(x, B2w, ob, omb);
    dcn_main_kernel<<<NB * HH * 2, 256, 0, stream>>>(x, omb, Bw, out);
  }
}

// Round 9
// 127.128 us; speedup vs baseline: 1.2995x; 1.0613x over previous
//
#include <hip/hip_runtime.h>
#include <hip/hip_bf16.h>
#include <math.h>

// Problem constants (N, C, H, W) = (4, 256, 64, 64), out_C = 256, FS=3, pad=1, stride=1
#define NB     4
#define CIN    256
#define HH     64
#define WW     64
#define OUTC   256
#define K2     9
#define KTOT   2304                // CIN * K2
#define HWSZ   4096                // HH * WW
#define NSTEPS 72                  // KTOT / 32
#define MTOT   16384               // NB * HWSZ

// K ordering everywhere: k' = tap*256 + c (tap-major).

typedef __attribute__((ext_vector_type(4)))  float  floatx4;
typedef __attribute__((ext_vector_type(16))) float  floatx16;
typedef __attribute__((ext_vector_type(8)))  short  short8;
typedef __attribute__((ext_vector_type(4)))  short  short4v;
typedef __attribute__((ext_vector_type(4)))  int    intx4;

__device__ __forceinline__ unsigned short f2bf(float f) {
  union { float f; unsigned u; } v; v.f = f;
  unsigned r = v.u + 0x7FFF + ((v.u >> 16) & 1);   // round-to-nearest-even
  return (unsigned short)(r >> 16);
}
__device__ __forceinline__ float b2f(unsigned short s) {
  union { unsigned u; float f; } v; v.u = ((unsigned)s) << 16;
  return v.f;
}

// ---------------------------------------------------------------------------
// MAIN-PATH workspace (bytes):
//   Bfrag  : [144 s16][8 nt][64 lane][8 bf16]  = 1,179,648  (32x32x16 frag order)
//   B2frag : [72 s32][2 nt][64 lane][8 bf16]   =   147,456  (16x16x32 frag order)
//   xt     : [4][64][64][256] bf16             = 8,388,608  (channel-last x)
#define WSM_BFRAG   0
#define WSM_B2FRAG  1179648
#define WSM_XT      (1179648 + 147456)
#define WSM_END     (WSM_XT + NB * HWSZ * CIN * 2)
// FALLBACK workspace (round-2 path, only if ws is tiny):
#define WSF_BW      0
#define WSF_B2W     (KTOT * OUTC * 2)
#define WSF_OM      (WSF_B2W + KTOT * 32 * 2)
#define WSF_END     (WSF_OM + NB * 27 * HWSZ * 4)

// ---------------------------------------------------------------------------
// Kernel 0 (main): xpose (blocks 0..255) + Bfrag pack (256..543) + B2frag
// pack (544..579).
// ---------------------------------------------------------------------------
__global__ __launch_bounds__(256) void prep_main_kernel(
    const float* __restrict__ dcn_w, const float* __restrict__ offw,
    const float* __restrict__ x,
    unsigned short* __restrict__ Bfrag, unsigned short* __restrict__ B2frag,
    unsigned short* __restrict__ xt) {
  int bid = blockIdx.x;
  int tid = threadIdx.x;
  if (bid < 256) {
    __shared__ unsigned short T[64 * 266];   // [w][c], pad 266
    int img = bid >> 6, h = bid & 63;
    const float* xp = x + (size_t)img * CIN * HWSZ + h * 64;
    int w = tid & 63, cq = tid >> 6;
    for (int cb = 0; cb < 256; cb += 4) {
      int c = cb + cq;
      T[w * 266 + c] = f2bf(xp[(size_t)c * HWSZ + w]);   // lanes=w: coalesced
    }
    __syncthreads();
    int w2 = tid >> 2, cg = (tid & 3) << 6;
    unsigned short* o = xt + ((size_t)(img * 64 + h) * 64 + w2) * 256 + cg;
#pragma unroll
    for (int i = 0; i < 64; i += 8) {
      short8 v = *(short8*)&T[w2 * 266 + cg + i];
      *(short8*)(o + i) = v;
    }
  } else if (bid < 544) {
    // Bfrag: e in [0, 73728): lane=e&63, nt=(e>>6)&7, s16=e>>9
    int e = (bid - 256) * 256 + tid;
    int lane = e & 63, nt = (e >> 6) & 7, s16 = e >> 9;
    int n = nt * 32 + (lane & 31);
    int kb = s16 * 16 + ((lane >> 5) << 3);
    short8 pk;
#pragma unroll
    for (int j = 0; j < 8; ++j) {
      int k = kb + j;
      pk[j] = (short)f2bf(dcn_w[n * KTOT + (k & 255) * 9 + (k >> 8)]);
    }
    *(short8*)(Bfrag + (size_t)e * 8) = pk;
  } else {
    // B2frag: e in [0, 9216): lane=e&63, nt=(e>>6)&1, s32=e>>7
    int e = (bid - 544) * 256 + tid;
    int lane = e & 63, nt = (e >> 6) & 1, s32 = e >> 7;
    int n = nt * 16 + (lane & 15);
    int kb = s32 * 32 + ((lane >> 4) << 3);
    short8 pk;
#pragma unroll
    for (int j = 0; j < 8; ++j) {
      int k = kb + j;
      pk[j] = (n < 27) ? (short)f2bf(offw[n * KTOT + (k & 255) * 9 + (k >> 8)])
                       : (short)0;
    }
    *(short8*)(B2frag + (size_t)e * 8) = pk;
  }
}

// ---------------------------------------------------------------------------
// Kernel 1 (main): FULLY FUSED offset-conv + sampling + GEMM, v5.
// Block = one (img,h) row: M=64, N=256 (sample-once), K=2304. Grid 256,
// 512 thr (8 waves, 2/SIMD -> intra-SIMD MFMA/VALU/LDS overlap).
// Phase A: offset conv on waves 0-3 (K-split MFMA, round-8 code), partials
//   -> LDS -> bilinear params.
// Phase B: wave q owns 64m x 32oc (disjoint oc -> B reg loads dup-free).
//   36 K64-steps, 8 MFMA 32x32x16 per wave-step. A sampled to dbuf LDS in
//   PADDED-GRANULE frag order (granule = blk*65 + row: writer quarter-waves
//   cover all 32 banks 2-way -> zero conflicts; reader sequential).
//   B frags from frag-packed global straight to regs (prefetch 1 step);
//   corner loads prefetch 2 steps. One barrier/step, orders only ds_writes.
// ---------------------------------------------------------------------------
__global__ __launch_bounds__(512, 2) void dcn_fused_kernel(
    const unsigned short* __restrict__ xt,
    const unsigned short* __restrict__ Bfrag,
    const unsigned short* __restrict__ B2frag,
    const float* __restrict__ ob, float* __restrict__ out) {
  __shared__ unsigned short Ald[2][520 * 8];    // 16.6 KB padded-granule dbuf
  __shared__ intx4  sOff[576];                  //  9 KB
  __shared__ float4 sWt[576];                   //  9 KB
  __shared__ float  omp[4 * 32 * 68];           // 34.8 KB conv partials

  int bid = blockIdx.x;                 // 0..255 = (img,h)
  int img = bid >> 6, h = bid & 63;
  const unsigned short* xb = xt + (size_t)img * HWSZ * 256;

  int tid  = threadIdx.x;
  int lane = tid & 63, q = tid >> 6;    // 8 waves
  int quad = lane >> 4, l15 = lane & 15;
  int l31  = lane & 31,  lh5 = lane >> 5;

  // ================= Phase A: offset conv (waves 0-3, K-split) =============
  if (q < 4) {
    floatx4 cacc[4][2];
#pragma unroll
    for (int mt = 0; mt < 4; ++mt)
#pragma unroll
      for (int nt = 0; nt < 2; ++nt) cacc[mt][nt] = (floatx4){0.f, 0.f, 0.f, 0.f};
    short8 cpa[2][4];
    short8 cpb[2][2];

#define CONV_LOAD(I, SLOT)                                                     \
  {                                                                            \
    int s = q + (I) * 4;                                                       \
    int t = s >> 3;                                                            \
    int dy = t / 3 - 1, dx = t % 3 - 1;                                        \
    int y = h + dy;                                                            \
    int cb0 = ((s & 7) << 5) + (quad << 3);                                    \
    _Pragma("unroll")                                                          \
    for (int mt = 0; mt < 4; ++mt) {                                           \
      int xx = mt * 16 + l15 + dx;                                             \
      short8 v = {0, 0, 0, 0, 0, 0, 0, 0};                                     \
      if (((unsigned)y < 64u) && ((unsigned)xx < 64u))                         \
        v = *(const short8*)(xb + ((y * 64 + xx) << 8) + cb0);                 \
      cpa[SLOT][mt] = v;                                                       \
    }                                                                          \
    _Pragma("unroll")                                                          \
    for (int nt = 0; nt < 2; ++nt)                                             \
      cpb[SLOT][nt] = *(const short8*)(B2frag + (((s * 2 + nt) * 64 + lane) << 3)); \
  }

    CONV_LOAD(0, 0);
#pragma unroll 2
    for (int i = 0; i < 18; ++i) {
      int sl = i & 1;
      if (i < 17) CONV_LOAD(i + 1, sl ^ 1);
#pragma unroll
      for (int mt = 0; mt < 4; ++mt)
#pragma unroll
        for (int nt = 0; nt < 2; ++nt)
          cacc[mt][nt] = __builtin_amdgcn_mfma_f32_16x16x32_bf16(
              cpa[sl][mt], cpb[sl][nt], cacc[mt][nt], 0, 0, 0);
    }
#undef CONV_LOAD
#pragma unroll
    for (int mt = 0; mt < 4; ++mt)
#pragma unroll
      for (int nt = 0; nt < 2; ++nt) {
        int oc = nt * 16 + l15;
        float4 vv = make_float4(cacc[mt][nt][0], cacc[mt][nt][1],
                                cacc[mt][nt][2], cacc[mt][nt][3]);
        *(float4*)&omp[(q * 32 + oc) * 68 + mt * 16 + quad * 4] = vv;
      }
  }
  __syncthreads();

  // ---- bilinear params: 9 taps x 64 w (sum 4 K-partials + bias) ----
  for (int v = tid; v < 576; v += 512) {
    int w = v & 63, t = v >> 6;
    int ky = t / 3, kx = t % 3;
    float offy = omp[(0 * 32 + 2 * t) * 68 + w] + omp[(1 * 32 + 2 * t) * 68 + w] +
                 omp[(2 * 32 + 2 * t) * 68 + w] + omp[(3 * 32 + 2 * t) * 68 + w] +
                 ob[2 * t];
    float offx = omp[(0 * 32 + 2 * t + 1) * 68 + w] + omp[(1 * 32 + 2 * t + 1) * 68 + w] +
                 omp[(2 * 32 + 2 * t + 1) * 68 + w] + omp[(3 * 32 + 2 * t + 1) * 68 + w] +
                 ob[2 * t + 1];
    float mraw = omp[(0 * 32 + 18 + t) * 68 + w] + omp[(1 * 32 + 18 + t) * 68 + w] +
                 omp[(2 * 32 + 18 + t) * 68 + w] + omp[(3 * 32 + 18 + t) * 68 + w] +
                 ob[18 + t];
    float mv   = 1.0f / (1.0f + __expf(-mraw));
    float him  = (float)(h - 1 + ky) + offy;
    float wim  = (float)(w - 1 + kx) + offx;
    float y0f = floorf(him), x0f = floorf(wim);
    float lhf = him - y0f, lwf = wim - x0f;
    int y0 = (int)y0f, x0i = (int)x0f;
    bool vy0 = (y0 >= 0) && (y0 < HH);
    bool vy1 = (y0 + 1 >= 0) && (y0 + 1 < HH);
    bool vx0 = (x0i >= 0) && (x0i < WW);
    bool vx1 = (x0i + 1 >= 0) && (x0i + 1 < WW);
    float hh_ = 1.0f - lhf, hw_ = 1.0f - lwf;
    float4 wt;
    wt.x = (vy0 && vx0) ? hh_ * hw_ * mv : 0.0f;
    wt.y = (vy0 && vx1) ? hh_ * lwf * mv : 0.0f;
    wt.z = (vy1 && vx0) ? lhf * hw_ * mv : 0.0f;
    wt.w = (vy1 && vx1) ? lhf * lwf * mv : 0.0f;
    int y0c = min(max(y0, 0), 63), y1c = min(max(y0 + 1, 0), 63);
    int x0c = min(max(x0i, 0), 63), x1c = min(max(x0i + 1, 0), 63);
    intx4 ii = {(y0c * 64 + x0c) << 8, (y0c * 64 + x1c) << 8,
                (y1c * 64 + x0c) << 8, (y1c * 64 + x1c) << 8};
    sOff[v] = ii;
    sWt[v]  = wt;
  }

  // ================= Phase B: fused sampling + GEMM ========================
  floatx16 acc[2];
#pragma unroll
  for (int mt = 0; mt < 2; ++mt)
#pragma unroll
    for (int e = 0; e < 16; ++e) acc[mt][e] = 0.f;

  int sm  = tid >> 3;          // sampler m row (0..63)
  int chk = tid & 7;           // 8-c chunk within K64 window
  // write granule: blk = sub*2 + mt, row = (chk&1)*32 + (m&31)
  int wgran = (((chk >> 1) << 1) + (sm >> 5)) * 65 + ((chk & 1) << 5) + (sm & 31);

  short8 bfr[2][4];            // B frags ping-pong [s&1][sub]
  short8 cr[4];                // corner regs
  float4 pwt;

  __syncthreads();             // params ready

  // ---- prologue ----
#pragma unroll
  for (int sub = 0; sub < 4; ++sub)
    bfr[0][sub] = *(const short8*)(
        Bfrag + (((size_t)sub * 8 + q) * 64 + lane) * 8);
  {
    intx4 off = sOff[sm];
    float4 w0 = sWt[sm];
    int cb = chk * 8;          // s=0: t=0, cq=0
    cr[0] = *(const short8*)(xb + off.x + cb);
    cr[1] = *(const short8*)(xb + off.y + cb);
    cr[2] = *(const short8*)(xb + off.z + cb);
    cr[3] = *(const short8*)(xb + off.w + cb);
    short8 pk;
#pragma unroll
    for (int j = 0; j < 8; ++j) {
      float v = w0.x * b2f((unsigned short)cr[0][j]) +
                w0.y * b2f((unsigned short)cr[1][j]) +
                w0.z * b2f((unsigned short)cr[2][j]) +
                w0.w * b2f((unsigned short)cr[3][j]);
      pk[j] = (short)f2bf(v);
    }
    *(short8*)&Ald[0][wgran * 8] = pk;
  }
  {
    // corners for s=1 (t=0, cq=1)
    intx4 off = sOff[sm];
    pwt = sWt[sm];
    int cb = 64 + chk * 8;
    cr[0] = *(const short8*)(xb + off.x + cb);
    cr[1] = *(const short8*)(xb + off.y + cb);
    cr[2] = *(const short8*)(xb + off.z + cb);
    cr[3] = *(const short8*)(xb + off.w + cb);
  }
  __syncthreads();

  // ---- main loop: 36 K64-steps ----
#pragma unroll 2
  for (int s = 0; s < 36; ++s) {
    int cur = s & 1;
    if (s < 35) {
      // B frags for s+1 (register loads, dup-free: wave q owns nt=q)
      int s16b = (s + 1) * 4;
#pragma unroll
      for (int sub = 0; sub < 4; ++sub)
        bfr[cur ^ 1][sub] = *(const short8*)(
            Bfrag + (((size_t)(s16b + sub) * 8 + q) * 64 + lane) * 8);
      // pack corners(s+1) -> Ald[cur^1]
      short8 pk;
#pragma unroll
      for (int j = 0; j < 8; ++j) {
        float v = pwt.x * b2f((unsigned short)cr[0][j]) +
                  pwt.y * b2f((unsigned short)cr[1][j]) +
                  pwt.z * b2f((unsigned short)cr[2][j]) +
                  pwt.w * b2f((unsigned short)cr[3][j]);
        pk[j] = (short)f2bf(v);
      }
      *(short8*)&Ald[cur ^ 1][wgran * 8] = pk;
    }
    if (s < 34) {
      // corner loads for s+2 (latency covered by this step's MFMA)
      int s2 = s + 2;
      int t2 = s2 >> 2;
      intx4 off = sOff[t2 * 64 + sm];
      pwt = sWt[t2 * 64 + sm];
      int cb = (s2 & 3) * 64 + chk * 8;
      cr[0] = *(const short8*)(xb + off.x + cb);
      cr[1] = *(const short8*)(xb + off.y + cb);
      cr[2] = *(const short8*)(xb + off.z + cb);
      cr[3] = *(const short8*)(xb + off.w + cb);
    }
    // 8 MFMA (32x32x16): a from padded-granule LDS, b from regs
#pragma unroll
    for (int sub = 0; sub < 4; ++sub) {
      short8 a0 = *(short8*)&Ald[cur][((sub * 2 + 0) * 65 + lane) * 8];
      short8 a1 = *(short8*)&Ald[cur][((sub * 2 + 1) * 65 + lane) * 8];
      acc[0] = __builtin_amdgcn_mfma_f32_32x32x16_bf16(
          a0, bfr[cur][sub], acc[0], 0, 0, 0);
      acc[1] = __builtin_amdgcn_mfma_f32_32x32x16_bf16(
          a1, bfr[cur][sub], acc[1], 0, 0, 0);
    }
    __syncthreads();   // orders only ds_writes — B is register-loaded
  }

  // ---- epilogue: D col = oc (lane&31), row = (r&3)+8*(r>>2)+4*(lane>>5) ----
  int oc = q * 32 + l31;
#pragma unroll
  for (int mt = 0; mt < 2; ++mt) {
    float* obase = out + (((size_t)img * OUTC + oc) << 12) + h * 64 +
                   mt * 32 + lh5 * 4;
#pragma unroll
    for (int rg = 0; rg < 4; ++rg) {
      float4 vv = make_float4(acc[mt][rg * 4 + 0], acc[mt][rg * 4 + 1],
                              acc[mt][rg * 4 + 2], acc[mt][rg * 4 + 3]);
      *(float4*)(obase + rg * 8) = vv;
    }
  }
}

// ===========================================================================
// FALLBACK PATH (round-2 kernels) — only if ws is too small (< ~9.7 MB).
// ===========================================================================
__global__ __launch_bounds__(256) void prep_fb_kernel(
    const float* __restrict__ dcn_w, const float* __restrict__ offw,
    unsigned short* __restrict__ Bw, unsigned short* __restrict__ B2w) {
  int oc = blockIdx.x;
  for (int k = threadIdx.x; k < KTOT; k += 256) {
    int t = k >> 8, c = k & 255;
    Bw[oc * KTOT + k] = f2bf(dcn_w[oc * KTOT + c * 9 + t]);
    if (oc < 32)
      B2w[oc * KTOT + k] = (oc < 27) ? f2bf(offw[oc * KTOT + c * 9 + t])
                                     : (unsigned short)0;
  }
}

__global__ __launch_bounds__(256) void conv_offset_kernel(
    const float* __restrict__ x, const unsigned short* __restrict__ B2w,
    const float* __restrict__ ob, float* __restrict__ om) {
  __shared__ unsigned short A_lds[64 * 40];
  __shared__ unsigned short B_lds[32 * 40];
  int bid = blockIdx.x;
  int n = bid >> 6, h = bid & 63;
  int tid = threadIdx.x, lane = tid & 63, q = tid >> 6;
  const float* xn = x + n * (CIN * HWSZ);
  floatx4 acc0 = {0.f, 0.f, 0.f, 0.f}, acc1 = {0.f, 0.f, 0.f, 0.f};
  int w = tid & 63, cg = tid >> 6, ocb = tid >> 3, part = tid & 7;
  for (int s = 0; s < NSTEPS; ++s) {
    int t = s >> 3, c0 = (s & 7) << 5;
    int dy = t / 3 - 1, dx = t % 3 - 1;
    __syncthreads();
    {
      int y = h + dy, xx = w + dx;
      bool inb = ((unsigned)y < 64u) && ((unsigned)xx < 64u);
      const float* xb = xn + (c0 + cg * 8) * HWSZ + y * 64 + xx;
      short8 pk;
#pragma unroll
      for (int j = 0; j < 8; ++j) { float v = inb ? xb[j * HWSZ] : 0.0f; pk[j] = (short)f2bf(v); }
      *(short8*)&A_lds[w * 40 + cg * 8] = pk;
    }
    { const unsigned short* bp = B2w + ocb * KTOT + (t << 8) + c0 + part * 4;
      *(short4v*)&B_lds[ocb * 40 + part * 4] = *(const short4v*)bp; }
    __syncthreads();
    int fr = (lane >> 4) * 8;
    short8 af  = *(short8*)&A_lds[(q * 16 + (lane & 15)) * 40 + fr];
    short8 bf0 = *(short8*)&B_lds[((lane & 15)) * 40 + fr];
    short8 bf1 = *(short8*)&B_lds[(16 + (lane & 15)) * 40 + fr];
    acc0 = __builtin_amdgcn_mfma_f32_16x16x32_bf16(af, bf0, acc0, 0, 0, 0);
    acc1 = __builtin_amdgcn_mfma_f32_16x16x32_bf16(af, bf1, acc1, 0, 0, 0);
  }
  int g = lane >> 4;
#pragma unroll
  for (int nt = 0; nt < 2; ++nt) {
    floatx4 a = nt ? acc1 : acc0;
    int oc = nt * 16 + (lane & 15);
    if (oc < 27) {
      float bias = ob[oc];
#pragma unroll
      for (int r = 0; r < 4; ++r) {
        int wm = q * 16 + g * 4 + r;
        float val = a[r] + bias;
        if (oc >= 18) val = 1.0f / (1.0f + __expf(-val));
        om[((n * 27 + oc) << 12) + h * 64 + wm] = val;
      }
    }
  }
}

__global__ __launch_bounds__(256) void dcn_main_kernel(
    const float* __restrict__ x, const float* __restrict__ om,
    const unsigned short* __restrict__ Bw, float* __restrict__ out) {
  __shared__ unsigned short A_lds[32 * 40];
  __shared__ unsigned short B_lds[256 * 40];
  __shared__ int    sY[288];
  __shared__ int    sX[288];
  __shared__ float4 sW[288];
  int bid = blockIdx.x;
  int n = bid >> 7, rem = bid & 127, h = rem >> 1, w0 = (rem & 1) << 5;
  int tid = threadIdx.x, lane = tid & 63, q = tid >> 6;
  const float* xn  = x + n * (CIN * HWSZ);
  const float* omn = om + n * (27 * HWSZ);
  for (int v = tid; v < 288; v += 256) {
    int m = v & 31, t = v >> 5;
    int ky = t / 3, kx = t % 3;
    int wg = w0 + m, sp = h * 64 + wg;
    float offy = omn[(2 * t) * HWSZ + sp];
    float offx = omn[(2 * t + 1) * HWSZ + sp];
    float mv   = omn[(18 + t) * HWSZ + sp];
    float him = (float)(h - 1 + ky) + offy;
    float wim = (float)(wg - 1 + kx) + offx;
    float y0f = floorf(him), x0f = floorf(wim);
    float lh = him - y0f, lw = wim - x0f;
    int y0 = (int)y0f, x0i = (int)x0f;
    bool vy0 = (y0 >= 0) && (y0 < HH), vy1 = (y0 + 1 >= 0) && (y0 + 1 < HH);
    bool vx0 = (x0i >= 0) && (x0i < WW), vx1 = (x0i + 1 >= 0) && (x0i + 1 < WW);
    float hh_ = 1.0f - lh, hw_ = 1.0f - lw;
    float4 wt;
    wt.x = (vy0 && vx0) ? hh_ * hw_ * mv : 0.0f;
    wt.y = (vy0 && vx1) ? hh_ * lw  * mv : 0.0f;
    wt.z = (vy1 && vx0) ? lh  * hw_ * mv : 0.0f;
    wt.w = (vy1 && vx1) ? lh  * lw  * mv : 0.0f;
    sY[v] = y0; sX[v] = x0i; sW[v] = wt;
  }
  floatx4 acc[2][4];
#pragma unroll
  for (int mi = 0; mi < 2; ++mi)
#pragma unroll
    for (int nj = 0; nj < 4; ++nj) acc[mi][nj] = (floatx4){0.f, 0.f, 0.f, 0.f};
  int m = tid & 31, cg = tid >> 5, n0 = q * 64;
  for (int s = 0; s < NSTEPS; ++s) {
    int t = s >> 3, c0 = (s & 7) << 5;
    __syncthreads();
    {
      int p = t * 32 + m;
      int y0 = sY[p], x0i = sX[p];
      float4 wt = sW[p];
      int y0c = min(max(y0, 0), 63), y1c = min(max(y0 + 1, 0), 63);
      int x0c = min(max(x0i, 0), 63), x1c = min(max(x0i + 1, 0), 63);
      int i00 = y0c * 64 + x0c, i01 = y0c * 64 + x1c;
      int i10 = y1c * 64 + x0c, i11 = y1c * 64 + x1c;
      const float* xb = xn + (c0 + cg * 4) * HWSZ;
      short4v pk;
#pragma unroll
      for (int j = 0; j < 4; ++j) {
        const float* xc = xb + j * HWSZ;
        float v = wt.x * xc[i00] + wt.y * xc[i01] + wt.z * xc[i10] + wt.w * xc[i11];
        pk[j] = (short)f2bf(v);
      }
      *(short4v*)&A_lds[m * 40 + cg * 4] = pk;
    }
    {
      const short8* bp = (const short8*)(Bw + tid * KTOT + (t << 8) + c0);
      short8 b0 = bp[0], b1 = bp[1], b2 = bp[2], b3 = bp[3];
      short8* dst = (short8*)&B_lds[tid * 40];
      dst[0] = b0; dst[1] = b1; dst[2] = b2; dst[3] = b3;
    }
    __syncthreads();
    int fr = (lane >> 4) * 8;
    short8 a0 = *(short8*)&A_lds[((lane & 15)) * 40 + fr];
    short8 a1 = *(short8*)&A_lds[(16 + (lane & 15)) * 40 + fr];
#pragma unroll
    for (int nj = 0; nj < 4; ++nj) {
      short8 bfp = *(short8*)&B_lds[(n0 + nj * 16 + (lane & 15)) * 40 + fr];
      acc[0][nj] = __builtin_amdgcn_mfma_f32_16x16x32_bf16(a0, bfp, acc[0][nj], 0, 0, 0);
      acc[1][nj] = __builtin_amdgcn_mfma_f32_16x16x32_bf16(a1, bfp, acc[1][nj], 0, 0, 0);
    }
  }
  int g = lane >> 4;
#pragma unroll
  for (int mi = 0; mi < 2; ++mi) {
    int wm = w0 + mi * 16 + g * 4;
#pragma unroll
    for (int nj = 0; nj < 4; ++nj) {
      int oc = n0 + nj * 16 + (lane & 15);
      float4 vv = make_float4(acc[mi][nj][0], acc[mi][nj][1],
                              acc[mi][nj][2], acc[mi][nj][3]);
      *(float4*)&out[((n * OUTC + oc) << 12) + h * 64 + wm] = vv;
    }
  }
}

// ---------------------------------------------------------------------------
extern "C" void kernel_launch(void* const* d_in, const int* in_sizes, int n_in,
                              void* d_out, int out_size, void* d_ws, size_t ws_size,
                              hipStream_t stream) {
  const float* x     = (const float*)d_in[0];
  const float* offw  = (const float*)d_in[1];
  const float* ob    = (const float*)d_in[2];
  const float* dcn_w = (const float*)d_in[3];
  float* out = (float*)d_out;

  if (ws_size >= (size_t)WSM_END) {
    unsigned short* Bfrag  = (unsigned short*)((char*)d_ws + WSM_BFRAG);
    unsigned short* B2frag = (unsigned short*)((char*)d_ws + WSM_B2FRAG);
    unsigned short* xtb    = (unsigned short*)((char*)d_ws + WSM_XT);
    // main path: 2 launches total
    prep_main_kernel<<<580, 256, 0, stream>>>(dcn_w, offw, x, Bfrag, B2frag, xtb);
    dcn_fused_kernel<<<256, 512, 0, stream>>>(xtb, Bfrag, B2frag, ob, out);
  } else {
    unsigned short* Bw  = (unsigned short*)((char*)d_ws + WSF_BW);
    unsigned short* B2w = (unsigned short*)((char*)d_ws + WSF_B2W);
    float*          omb = (float*)((char*)d_ws + WSF_OM);
    prep_fb_kernel<<<256, 256, 0, stream>>>(dcn_w, offw, Bw, B2w);
    conv_offset_kernel<<<NB * HH, 256, 0, stream>>>(x, B2w, ob, omb);
    dcn_main_kernel<<<NB * HH * 2, 256, 0, stream>>>(x, omb, Bw, out);
  }
}